// Round 1
// baseline (2421.105 us; speedup 1.0000x reference)
//
#include <hip/hip_runtime.h>
#include <cstdint>

#define L_ 4
#define D_ 2048
#define H_ 16
#define KVH_ 8
#define DH_ 128
#define F_ 6144
#define V_ 32000
#define SMAX_ 2048
#define T_ 1024
#define EPS_ 1e-6f

typedef unsigned short u16;
typedef unsigned int u32;
typedef float fvec4 __attribute__((ext_vector_type(4)));
typedef float f32x4 __attribute__((ext_vector_type(4)));
typedef __bf16 bf16x8 __attribute__((ext_vector_type(8)));

__device__ __forceinline__ u16 f2bf(float f) {
  union { float f; u32 u; } a; a.f = f;
  u32 u = a.u;
  return (u16)((u + 0x7FFFu + ((u >> 16) & 1u)) >> 16);
}

__device__ __forceinline__ void gld16(const void* g, void* l) {
  __builtin_amdgcn_global_load_lds(
      (const __attribute__((address_space(1))) void*)g,
      (__attribute__((address_space(3))) void*)l, 16, 0, 0);
}

__device__ __forceinline__ float blk_sum(float v, volatile float* sm) {
#pragma unroll
  for (int m = 32; m; m >>= 1) v += __shfl_xor(v, m);
  if ((threadIdx.x & 63) == 0) sm[threadIdx.x >> 6] = v;
  __syncthreads();
  v = sm[0] + sm[1] + sm[2] + sm[3];
  __syncthreads();
  return v;
}
__device__ __forceinline__ float blk_max(float v, volatile float* sm) {
#pragma unroll
  for (int m = 32; m; m >>= 1) v = fmaxf(v, __shfl_xor(v, m));
  if ((threadIdx.x & 63) == 0) sm[threadIdx.x >> 6] = v;
  __syncthreads();
  v = fmaxf(fmaxf(sm[0], sm[1]), fmaxf(sm[2], sm[3]));
  __syncthreads();
  return v;
}

// ---------------- embedding (with uint8-vs-int32 runtime detection) ----------
__global__ void embed_k(const int* __restrict__ ids, const void* __restrict__ edata,
                        const float* __restrict__ esc, const float* __restrict__ ez,
                        float* __restrict__ hidden)
{
  const int* ei = (const int*)edata;
  int chk = ei[threadIdx.x & 63];
  bool ok = ((unsigned)chk) <= 255u;
  bool is_i32 = (__ballot(ok) == ~0ULL);
  int t = blockIdx.x;
  int id = ids[t];
  float sc = esc[id], zp = ez[id];
  size_t base = (size_t)id * D_;
  const uint8_t* eb = (const uint8_t*)edata;
  for (int d = threadIdx.x; d < D_; d += 256) {
    float e = is_i32 ? (float)ei[base + d] : (float)eb[base + d];
    hidden[(size_t)t * D_ + d] = e * sc + zp;
  }
}

// ---------------- convert + transpose: W f32 (K,N) -> WT bf16 (N,K) ----------
__global__ void convT_k(const float* __restrict__ W, u16* __restrict__ WT, int K, int N)
{
  __shared__ float tile[32][33];
  int n0 = blockIdx.x * 32, k0 = blockIdx.y * 32;
#pragma unroll
  for (int j = threadIdx.y; j < 32; j += 8)
    tile[j][threadIdx.x] = W[(size_t)(k0 + j) * N + n0 + threadIdx.x];
  __syncthreads();
#pragma unroll
  for (int j = threadIdx.y; j < 32; j += 8)
    WT[(size_t)(n0 + j) * K + k0 + threadIdx.x] = f2bf(tile[threadIdx.x][j]);
}

// ---------------- RMS norm (row of D_) f32 -> bf16 -------------------------
__global__ void rms_k(const float* __restrict__ x, const float* __restrict__ w,
                      u16* __restrict__ out)
{
  __shared__ float sm[4];
  int t = blockIdx.x;
  const fvec4* xr = (const fvec4*)(x + (size_t)t * D_);
  fvec4 v0 = xr[threadIdx.x], v1 = xr[threadIdx.x + 256];
  float s = v0[0]*v0[0] + v0[1]*v0[1] + v0[2]*v0[2] + v0[3]*v0[3]
          + v1[0]*v1[0] + v1[1]*v1[1] + v1[2]*v1[2] + v1[3]*v1[3];
  s = blk_sum(s, sm);
  float inv = rsqrtf(s * (1.f / D_) + EPS_);
  const fvec4* wr = (const fvec4*)w;
  fvec4 w0 = wr[threadIdx.x], w1 = wr[threadIdx.x + 256];
  u16* orow = out + (size_t)t * D_;
  uint2 o0, o1;
  o0.x = (u32)f2bf(w0[0]*v0[0]*inv) | ((u32)f2bf(w0[1]*v0[1]*inv) << 16);
  o0.y = (u32)f2bf(w0[2]*v0[2]*inv) | ((u32)f2bf(w0[3]*v0[3]*inv) << 16);
  o1.x = (u32)f2bf(w1[0]*v1[0]*inv) | ((u32)f2bf(w1[1]*v1[1]*inv) << 16);
  o1.y = (u32)f2bf(w1[2]*v1[2]*inv) | ((u32)f2bf(w1[3]*v1[3]*inv) << 16);
  *(uint2*)(orow + threadIdx.x * 4) = o0;
  *(uint2*)(orow + (threadIdx.x + 256) * 4) = o1;
}

// ---------------- GEMM: C(MxN) = A(MxK,bf16) * B^T(NxK,bf16) ----------------
// EPI 0: Cf=acc (f32)   EPI 1: Cb=bf16(acc)   EPI 2: Cf+=acc (residual)
template<int EPI>
__global__ __launch_bounds__(256)
void gemm_bt(const u16* __restrict__ A, const u16* __restrict__ B,
             float* __restrict__ Cf, u16* __restrict__ Cb,
             int K, int ldC,
             long long sA, long long sB, long long sC, int bdiv)
{
  __shared__ u16 lA[128 * 64];
  __shared__ u16 lB[128 * 64];
  int bz = blockIdx.z;
  const u16* Ab = A + (long long)bz * sA + (size_t)blockIdx.y * 128 * K;
  const u16* Bb = B + (long long)(bz / bdiv) * sB + (size_t)blockIdx.x * 128 * K;
  long long cOff = (long long)bz * sC;

  int tid = threadIdx.x;
  int l = tid & 63;
  int wid = tid >> 6;
  int wr = wid >> 1, wc = wid & 1;
  int lrow = l & 15, lk = l >> 4;

  f32x4 acc[4][4] = {};

  for (int k0 = 0; k0 < K; k0 += 64) {
#pragma unroll
    for (int r = 0; r < 4; ++r) {
      int c = r * 256 + tid;
      int row = c >> 3, g = c & 7;
      int kel = k0 + ((g ^ (row & 7)) << 3);
      gld16(Ab + (size_t)row * K + kel, (char*)lA + c * 16);
      gld16(Bb + (size_t)row * K + kel, (char*)lB + c * 16);
    }
    __syncthreads();
#pragma unroll
    for (int kk = 0; kk < 2; ++kk) {
      bf16x8 av[4], bv[4];
      int kbyte = (kk * 32 + lk * 8) * 2;
#pragma unroll
      for (int m = 0; m < 4; ++m) {
        int row = wr * 64 + m * 16 + lrow;
        int byt = (row * 128 + kbyte) ^ ((row & 7) << 4);
        av[m] = *(const bf16x8*)((const char*)lA + byt);
      }
#pragma unroll
      for (int n = 0; n < 4; ++n) {
        int row = wc * 64 + n * 16 + lrow;
        int byt = (row * 128 + kbyte) ^ ((row & 7) << 4);
        bv[n] = *(const bf16x8*)((const char*)lB + byt);
      }
#pragma unroll
      for (int m = 0; m < 4; ++m)
#pragma unroll
        for (int n = 0; n < 4; ++n)
          acc[m][n] = __builtin_amdgcn_mfma_f32_16x16x32_bf16(av[m], bv[n], acc[m][n], 0, 0, 0);
    }
    __syncthreads();
  }

  int grow0 = blockIdx.y * 128 + wr * 64 + lk * 4;
  int gcol0 = blockIdx.x * 128 + wc * 64 + lrow;
#pragma unroll
  for (int m = 0; m < 4; ++m)
#pragma unroll
    for (int n = 0; n < 4; ++n)
#pragma unroll
      for (int r = 0; r < 4; ++r) {
        long long off = cOff + (long long)(grow0 + m * 16 + r) * ldC + gcol0 + n * 16;
        if (EPI == 0) Cf[off] = acc[m][n][r];
        else if (EPI == 1) Cb[off] = f2bf(acc[m][n][r]);
        else Cf[off] += acc[m][n][r];
      }
}

// ---------------- per-(t,head) RMS + RoPE for Q -----------------------------
__global__ void qrope_k(const float* __restrict__ qf, const float* __restrict__ wq,
                        const float* __restrict__ cosT, const float* __restrict__ sinT,
                        const int* __restrict__ plp, u16* __restrict__ qr)
{
  int t = blockIdx.x, h = blockIdx.y, l = threadIdx.x;
  const float* row = qf + (size_t)t * (H_ * DH_) + h * DH_;
  float x1 = row[l], x2 = row[l + 64];
  float ss = x1 * x1 + x2 * x2;
#pragma unroll
  for (int m = 32; m; m >>= 1) ss += __shfl_xor(ss, m);
  float inv = rsqrtf(ss * (1.f / DH_) + EPS_);
  int p = plp[0] + t;
  float xn1 = wq[l] * x1 * inv, xn2 = wq[l + 64] * x2 * inv;
  float r1 = xn1 * cosT[(size_t)p * DH_ + l]      - xn2 * sinT[(size_t)p * DH_ + l];
  float r2 = xn2 * cosT[(size_t)p * DH_ + l + 64] + xn1 * sinT[(size_t)p * DH_ + l + 64];
  size_t o = ((size_t)h * T_ + t) * DH_;
  qr[o + l] = f2bf(r1);
  qr[o + l + 64] = f2bf(r2);
}

// ---------------- per-(t,kv) RMS + RoPE for K; writes k_rot bf16 + key_out f32
__global__ void krope_k(const float* __restrict__ kf, const float* __restrict__ wk,
                        const float* __restrict__ cosT, const float* __restrict__ sinT,
                        const int* __restrict__ plp, u16* __restrict__ kr,
                        float* __restrict__ key_out)
{
  int t = blockIdx.x, kv = blockIdx.y, l = threadIdx.x;
  const float* row = kf + (size_t)t * (KVH_ * DH_) + kv * DH_;
  float x1 = row[l], x2 = row[l + 64];
  float ss = x1 * x1 + x2 * x2;
#pragma unroll
  for (int m = 32; m; m >>= 1) ss += __shfl_xor(ss, m);
  float inv = rsqrtf(ss * (1.f / DH_) + EPS_);
  int p = plp[0] + t;
  float xn1 = wk[l] * x1 * inv, xn2 = wk[l + 64] * x2 * inv;
  float r1 = xn1 * cosT[(size_t)p * DH_ + l]      - xn2 * sinT[(size_t)p * DH_ + l];
  float r2 = xn2 * cosT[(size_t)p * DH_ + l + 64] + xn1 * sinT[(size_t)p * DH_ + l + 64];
  size_t o = ((size_t)kv * T_ + t) * DH_;
  kr[o + l] = f2bf(r1);
  kr[o + l + 64] = f2bf(r2);
  key_out[((size_t)kv * DH_ + l) * SMAX_ + p] = r1;
  key_out[((size_t)kv * DH_ + l + 64) * SMAX_ + p] = r2;
}

// ---------------- V: write value_out f32 + vT bf16 (kv, d, t) ----------------
__global__ void vwrite_k(const float* __restrict__ vf, u16* __restrict__ vT,
                         float* __restrict__ vout, const int* __restrict__ plp)
{
  int t = blockIdx.x, kv = blockIdx.y, d = threadIdx.x; // 128 threads
  float val = vf[(size_t)t * (KVH_ * DH_) + kv * DH_ + d];
  vT[((size_t)kv * DH_ + d) * T_ + t] = f2bf(val);
  vout[((size_t)kv * SMAX_ + plp[0] + t) * DH_ + d] = val;
}

// ---------------- masked softmax over s, f32 scores -> bf16 probs -----------
__global__ void softmax_k(const float* __restrict__ scores, const float* __restrict__ am,
                          u16* __restrict__ probs, const int* __restrict__ plp)
{
  __shared__ float sm[4];
  int t = blockIdx.x, h = blockIdx.y;
  int pl = plp[0];
  const float* srow = scores + ((size_t)h * T_ + t) * T_;
  const float* arow = am + (size_t)t * T_;
  int s0 = threadIdx.x * 4;
  fvec4 sc = *(const fvec4*)(srow + s0);
  fvec4 a = *(const fvec4*)(arow + s0);
  float vals[4];
#pragma unroll
  for (int j = 0; j < 4; j++) {
    float m_ = (s0 + j <= t + pl) ? 0.f : -128.f * a[j];
    vals[j] = sc[j] + m_;
  }
  float mx = fmaxf(fmaxf(vals[0], vals[1]), fmaxf(vals[2], vals[3]));
  mx = blk_max(mx, sm);
  float ex[4], ssum = 0.f;
#pragma unroll
  for (int j = 0; j < 4; j++) { ex[j] = __expf(vals[j] - mx); ssum += ex[j]; }
  ssum = blk_sum(ssum, sm);
  float inv = 1.f / ssum;
  uint2 o;
  o.x = (u32)f2bf(ex[0] * inv) | ((u32)f2bf(ex[1] * inv) << 16);
  o.y = (u32)f2bf(ex[2] * inv) | ((u32)f2bf(ex[3] * inv) << 16);
  *(uint2*)(probs + ((size_t)h * T_ + t) * T_ + s0) = o;
}

// ---------------- silu(gate)*up -> bf16 --------------------------------------
__global__ void silu_k(const float* __restrict__ g, const float* __restrict__ u,
                       u16* __restrict__ o)
{
  size_t i = (size_t)blockIdx.x * 256 + threadIdx.x;
  fvec4 gv = ((const fvec4*)g)[i];
  fvec4 uv = ((const fvec4*)u)[i];
  float r[4];
#pragma unroll
  for (int j = 0; j < 4; j++) {
    float x = gv[j];
    r[j] = x / (1.f + __expf(-x)) * uv[j];
  }
  uint2 ov;
  ov.x = (u32)f2bf(r[0]) | ((u32)f2bf(r[1]) << 16);
  ov.y = (u32)f2bf(r[2]) | ((u32)f2bf(r[3]) << 16);
  ((uint2*)o)[i] = ov;
}

// ---------------- final RMS (last token) f32 out ------------------------------
__global__ void frms_k(const float* __restrict__ x, const float* __restrict__ w,
                       float* __restrict__ out)
{
  __shared__ float sm[4];
  float s = 0.f;
  for (int d = threadIdx.x; d < D_; d += 256) { float v = x[d]; s += v * v; }
  s = blk_sum(s, sm);
  float inv = rsqrtf(s * (1.f / D_) + EPS_);
  for (int d = threadIdx.x; d < D_; d += 256) out[d] = w[d] * x[d] * inv;
}

// ---------------- LM head partial GEMV (f32, deterministic) ------------------
__global__ void lmgemv_k(const float* __restrict__ last, const float* __restrict__ Wlm,
                         float* __restrict__ part)
{
  __shared__ float ls[256];
  int v = blockIdx.x * 256 + threadIdx.x;
  int c = blockIdx.y;
  ls[threadIdx.x] = last[c * 256 + threadIdx.x];
  __syncthreads();
  const float* Wp = Wlm + (size_t)c * 256 * V_ + v;
  float acc = 0.f;
#pragma unroll 8
  for (int d = 0; d < 256; d++) acc += ls[d] * Wp[(size_t)d * V_];
  part[(size_t)c * V_ + v] = acc;
}

// ---------------- argmax stage 1: sum 8 partials, block argmax ---------------
__global__ void amax_part_k(const float* __restrict__ part, float2* __restrict__ out)
{
  __shared__ float sv[4];
  __shared__ int si[4];
  int v = blockIdx.x * 256 + threadIdx.x;
  float val = 0.f;
#pragma unroll
  for (int c = 0; c < 8; c++) val += part[(size_t)c * V_ + v];
  float bv = val; int bi = v;
#pragma unroll
  for (int m = 32; m; m >>= 1) {
    float ov = __shfl_xor(bv, m);
    int oi = __shfl_xor(bi, m);
    if (ov > bv || (ov == bv && oi < bi)) { bv = ov; bi = oi; }
  }
  if ((threadIdx.x & 63) == 0) { sv[threadIdx.x >> 6] = bv; si[threadIdx.x >> 6] = bi; }
  __syncthreads();
  if (threadIdx.x == 0) {
    for (int w = 1; w < 4; w++)
      if (sv[w] > bv || (sv[w] == bv && si[w] < bi)) { bv = sv[w]; bi = si[w]; }
    out[blockIdx.x] = make_float2(bv, (float)bi);
  }
}

// ---------------- argmax stage 2 + scalar outputs ----------------------------
__global__ void finalize_k(const float2* __restrict__ part, int np,
                           const int* __restrict__ plp, float* __restrict__ dout,
                           unsigned long long lastoff)
{
  if (threadIdx.x == 0) {
    float bv = part[0].x; int bi = (int)part[0].y;
    for (int b = 1; b < np; b++) {
      float v = part[b].x; int i = (int)part[b].y;
      if (v > bv || (v == bv && i < bi)) { bv = v; bi = i; }
    }
    dout[0] = (float)bi;
    dout[lastoff] = (float)(plp[0] + T_);
  }
}

// =============================================================================
extern "C" void kernel_launch(void* const* d_in, const int* in_sizes, int n_in,
                              void* d_out, int out_size, void* d_ws, size_t ws_size,
                              hipStream_t stream)
{
  (void)in_sizes; (void)n_in; (void)out_size; (void)ws_size;

  const float* key_in  = (const float*)d_in[0];
  const float* val_in  = (const float*)d_in[1];
  const int*   ids     = (const int*)d_in[2];
  const float* am      = (const float*)d_in[3];
  const int*   plp     = (const int*)d_in[4];
  const void*  edata   = d_in[5];
  const float* esc     = (const float*)d_in[6];
  const float* ez      = (const float*)d_in[7];
  const float* cosT    = (const float*)d_in[8];
  const float* sinT    = (const float*)d_in[9];
  const float* w_in_ln = (const float*)d_in[10];
  const float* Wq      = (const float*)d_in[11];
  const float* Wk      = (const float*)d_in[12];
  const float* Wv      = (const float*)d_in[13];
  const float* wqn     = (const float*)d_in[14];
  const float* wkn     = (const float*)d_in[15];
  const float* Wo      = (const float*)d_in[16];
  const float* wpost   = (const float*)d_in[17];
  const float* Wg      = (const float*)d_in[18];
  const float* Wu      = (const float*)d_in[19];
  const float* Wd      = (const float*)d_in[20];
  const float* wfin    = (const float*)d_in[21];
  const float* Wlm     = (const float*)d_in[22];

  float* out = (float*)d_out;
  const size_t KVN = (size_t)L_ * KVH_ * DH_ * SMAX_; // 8388608
  float* key_out = out + 1;
  float* val_out = out + 1 + KVN;
  unsigned long long lastoff = 1 + 2 * KVN;

  char* ws = (char*)d_ws;
  u16*   wT     = (u16*)  (ws + 0);           // 25165824 B
  u16*   hn     = (u16*)  (ws + 25165824);    //  4194304 B
  float* qf     = (float*)(ws + 29360128);    //  8388608 B
  float* kf     = (float*)(ws + 37748736);    //  4194304 B
  float* vf     = (float*)(ws + 41943040);    //  4194304 B
  u16*   qr     = (u16*)  (ws + 46137344);    //  4194304 B
  u16*   kr     = (u16*)  (ws + 50331648);    //  2097152 B
  u16*   vT     = (u16*)  (ws + 52428800);    //  2097152 B
  u16*   ctx    = (u16*)  (ws + 54525952);    //  4194304 B
  float* hidden = (float*)(ws + 58720256);    //  8388608 B
  float* last   = (float*)(ws + 67108864);    //     8192 B
  float* lpart  = (float*)(ws + 67117056);    //  1024000 B
  float2* amaxp = (float2*)(ws + 68141312);   //     1000 B
  char*  arena  = ws + 68157440;              // 100663296 B
  float* scores = (float*)arena;              // 67108864 B
  u16*   probs  = (u16*)(arena + 67108864);   // 33554432 B
  float* gate   = (float*)arena;              // aliases scores (dead by then)
  float* up     = (float*)(arena + 25165824);
  u16*   mlp    = (u16*)(arena + 50331648);

  hipMemcpyAsync(key_out, key_in, KVN * sizeof(float), hipMemcpyDeviceToDevice, stream);
  hipMemcpyAsync(val_out, val_in, KVN * sizeof(float), hipMemcpyDeviceToDevice, stream);
  embed_k<<<T_, 256, 0, stream>>>(ids, edata, esc, ez, hidden);

  for (int i = 0; i < L_; i++) {
    // --- attention block ---
    rms_k<<<T_, 256, 0, stream>>>(hidden, w_in_ln + (size_t)i * D_, hn);

    convT_k<<<dim3(64, 64), dim3(32, 8), 0, stream>>>(Wq + (size_t)i * 4194304, wT, 2048, 2048);
    gemm_bt<0><<<dim3(16, 8, 1), 256, 0, stream>>>(hn, wT, qf, nullptr, 2048, 2048, 0, 0, 0, 1);

    convT_k<<<dim3(32, 64), dim3(32, 8), 0, stream>>>(Wk + (size_t)i * 2097152, wT, 2048, 1024);
    gemm_bt<0><<<dim3(8, 8, 1), 256, 0, stream>>>(hn, wT, kf, nullptr, 2048, 1024, 0, 0, 0, 1);

    convT_k<<<dim3(32, 64), dim3(32, 8), 0, stream>>>(Wv + (size_t)i * 2097152, wT, 2048, 1024);
    gemm_bt<0><<<dim3(8, 8, 1), 256, 0, stream>>>(hn, wT, vf, nullptr, 2048, 1024, 0, 0, 0, 1);

    qrope_k<<<dim3(T_, H_), 64, 0, stream>>>(qf, wqn + (size_t)i * DH_, cosT, sinT, plp, qr);
    krope_k<<<dim3(T_, KVH_), 64, 0, stream>>>(kf, wkn + (size_t)i * DH_, cosT, sinT, plp, kr,
                                               key_out + (size_t)i * KVH_ * DH_ * SMAX_);
    vwrite_k<<<dim3(T_, KVH_), 128, 0, stream>>>(vf, vT,
                                                 val_out + (size_t)i * KVH_ * SMAX_ * DH_, plp);

    // scores[h,t,s] = q_rot[h,t,:] . k_rot[h>>1,s,:]
    gemm_bt<0><<<dim3(8, 8, H_), 256, 0, stream>>>(qr, kr, scores, nullptr,
        DH_, T_, (long long)T_ * DH_, (long long)T_ * DH_, (long long)T_ * T_, 2);

    softmax_k<<<dim3(T_, H_), 256, 0, stream>>>(scores, am, probs, plp);

    // ctx[t, h*DH+d] = probs[h,t,:] . vT[h>>1,d,:]
    gemm_bt<1><<<dim3(1, 8, H_), 256, 0, stream>>>(probs, vT, nullptr, ctx,
        T_, H_ * DH_, (long long)T_ * T_, (long long)DH_ * T_, DH_, 2);

    convT_k<<<dim3(64, 64), dim3(32, 8), 0, stream>>>(Wo + (size_t)i * 4194304, wT, 2048, 2048);
    gemm_bt<2><<<dim3(16, 8, 1), 256, 0, stream>>>(ctx, wT, hidden, nullptr, 2048, 2048, 0, 0, 0, 1);

    // --- MLP block ---
    rms_k<<<T_, 256, 0, stream>>>(hidden, wpost + (size_t)i * D_, hn);

    convT_k<<<dim3(192, 64), dim3(32, 8), 0, stream>>>(Wg + (size_t)i * 12582912, wT, 2048, 6144);
    gemm_bt<0><<<dim3(48, 8, 1), 256, 0, stream>>>(hn, wT, gate, nullptr, 2048, F_, 0, 0, 0, 1);

    convT_k<<<dim3(192, 64), dim3(32, 8), 0, stream>>>(Wu + (size_t)i * 12582912, wT, 2048, 6144);
    gemm_bt<0><<<dim3(48, 8, 1), 256, 0, stream>>>(hn, wT, up, nullptr, 2048, F_, 0, 0, 0, 1);

    silu_k<<<(T_ * F_) / 1024, 256, 0, stream>>>(gate, up, mlp);

    convT_k<<<dim3(64, 192), dim3(32, 8), 0, stream>>>(Wd + (size_t)i * 12582912, wT, 6144, 2048);
    gemm_bt<2><<<dim3(16, 8, 1), 256, 0, stream>>>(mlp, wT, hidden, nullptr, 6144, 2048, 0, 0, 0, 1);
  }

  frms_k<<<1, 256, 0, stream>>>(hidden + (size_t)(T_ - 1) * D_, wfin, last);
  lmgemv_k<<<dim3(V_ / 256, 8), 256, 0, stream>>>(last, Wlm, lpart);
  amax_part_k<<<V_ / 256, 256, 0, stream>>>(lpart, amaxp);
  finalize_k<<<1, 64, 0, stream>>>(amaxp, V_ / 256, plp, out, lastoff);
}

// Round 2
// 1787.550 us; speedup vs baseline: 1.3544x; 1.3544x over previous
//
#include <hip/hip_runtime.h>
#include <cstdint>

#define L_ 4
#define D_ 2048
#define H_ 16
#define KVH_ 8
#define DH_ 128
#define F_ 6144
#define V_ 32000
#define SMAX_ 2048
#define T_ 1024
#define EPS_ 1e-6f
#define QB 64
#define SB 128

typedef unsigned short u16;
typedef unsigned int u32;
typedef float fvec4 __attribute__((ext_vector_type(4)));
typedef float f32x4 __attribute__((ext_vector_type(4)));
typedef __bf16 bf16x8 __attribute__((ext_vector_type(8)));

__device__ __forceinline__ u16 f2bf(float f) {
  union { float f; u32 u; } a; a.f = f;
  u32 u = a.u;
  return (u16)((u + 0x7FFFu + ((u >> 16) & 1u)) >> 16);
}
__device__ __forceinline__ float bf2f(u16 h) {
  union { u32 u; float f; } a; a.u = (u32)h << 16; return a.f;
}

__device__ __forceinline__ void gld16(const void* g, void* l) {
  __builtin_amdgcn_global_load_lds(
      (const __attribute__((address_space(1))) void*)g,
      (__attribute__((address_space(3))) void*)l, 16, 0, 0);
}

__device__ __forceinline__ float blk_sum(float v, volatile float* sm) {
#pragma unroll
  for (int m = 32; m; m >>= 1) v += __shfl_xor(v, m);
  if ((threadIdx.x & 63) == 0) sm[threadIdx.x >> 6] = v;
  __syncthreads();
  v = sm[0] + sm[1] + sm[2] + sm[3];
  __syncthreads();
  return v;
}

// ---------------- embedding (uint8-vs-int32 runtime detection) ---------------
__global__ void embed_k(const int* __restrict__ ids, const void* __restrict__ edata,
                        const float* __restrict__ esc, const float* __restrict__ ez,
                        float* __restrict__ hidden)
{
  const int* ei = (const int*)edata;
  int chk = ei[threadIdx.x & 63];
  bool ok = ((unsigned)chk) <= 255u;
  bool is_i32 = (__ballot(ok) == ~0ULL);
  int t = blockIdx.x;
  int id = ids[t];
  float sc = esc[id], zp = ez[id];
  size_t base = (size_t)id * D_;
  const uint8_t* eb = (const uint8_t*)edata;
  for (int d = threadIdx.x; d < D_; d += 256) {
    float e = is_i32 ? (float)ei[base + d] : (float)eb[base + d];
    hidden[(size_t)t * D_ + d] = e * sc + zp;
  }
}

// -------- convert + transpose: W f32 (K,N) -> WT bf16 (N,K), 64x64 tiles -----
__global__ void convT_k(const float* __restrict__ W, u16* __restrict__ WT, int K, int N)
{
  __shared__ u16 tile[64][66];
  int n0 = blockIdx.x * 64, k0 = blockIdx.y * 64;
  int tx = threadIdx.x & 63, ty = threadIdx.x >> 6;
#pragma unroll
  for (int j = ty; j < 64; j += 4)
    tile[tx][j] = f2bf(W[(size_t)(k0 + j) * N + n0 + tx]);
  __syncthreads();
  int n = threadIdx.x >> 2, kq = (threadIdx.x & 3) * 16;
  u16* orow = WT + (size_t)(n0 + n) * K + k0 + kq;
  union { u16 h[8]; uint4 q; } u0, u1;
#pragma unroll
  for (int i = 0; i < 8; ++i) u0.h[i] = tile[n][kq + i];
#pragma unroll
  for (int i = 0; i < 8; ++i) u1.h[i] = tile[n][kq + 8 + i];
  *(uint4*)orow = u0.q;
  *(uint4*)(orow + 8) = u1.q;
}

// ---------------- RMS norm (row of D_) f32 -> bf16 ---------------------------
__global__ void rms_k(const float* __restrict__ x, const float* __restrict__ w,
                      u16* __restrict__ out)
{
  __shared__ float sm[4];
  int t = blockIdx.x;
  const fvec4* xr = (const fvec4*)(x + (size_t)t * D_);
  fvec4 v0 = xr[threadIdx.x], v1 = xr[threadIdx.x + 256];
  float s = v0[0]*v0[0] + v0[1]*v0[1] + v0[2]*v0[2] + v0[3]*v0[3]
          + v1[0]*v1[0] + v1[1]*v1[1] + v1[2]*v1[2] + v1[3]*v1[3];
  s = blk_sum(s, sm);
  float inv = rsqrtf(s * (1.f / D_) + EPS_);
  const fvec4* wr = (const fvec4*)w;
  fvec4 w0 = wr[threadIdx.x], w1 = wr[threadIdx.x + 256];
  u16* orow = out + (size_t)t * D_;
  uint2 o0, o1;
  o0.x = (u32)f2bf(w0[0]*v0[0]*inv) | ((u32)f2bf(w0[1]*v0[1]*inv) << 16);
  o0.y = (u32)f2bf(w0[2]*v0[2]*inv) | ((u32)f2bf(w0[3]*v0[3]*inv) << 16);
  o1.x = (u32)f2bf(w1[0]*v1[0]*inv) | ((u32)f2bf(w1[1]*v1[1]*inv) << 16);
  o1.y = (u32)f2bf(w1[2]*v1[2]*inv) | ((u32)f2bf(w1[3]*v1[3]*inv) << 16);
  *(uint2*)(orow + threadIdx.x * 4) = o0;
  *(uint2*)(orow + (threadIdx.x + 256) * 4) = o1;
}

// ---------------- GEMM: C(MxN) = A(MxK,bf16) * B^T(NxK,bf16) -----------------
// EPI 0: Cf=acc   EPI 1: Cb=bf16(acc)   EPI 2: Cf+=acc
template<int EPI>
__global__ __launch_bounds__(256)
void gemm_bt(const u16* __restrict__ A, const u16* __restrict__ B,
             float* __restrict__ Cf, u16* __restrict__ Cb, int K, int ldC)
{
  __shared__ u16 lA[128 * 64];
  __shared__ u16 lB[128 * 64];
  const u16* Ab = A + (size_t)blockIdx.y * 128 * K;
  const u16* Bb = B + (size_t)blockIdx.x * 128 * K;

  int tid = threadIdx.x;
  int l = tid & 63;
  int wid = tid >> 6;
  int wr = wid >> 1, wc = wid & 1;
  int lrow = l & 15, lk = l >> 4;

  f32x4 acc[4][4] = {};

  for (int k0 = 0; k0 < K; k0 += 64) {
#pragma unroll
    for (int r = 0; r < 4; ++r) {
      int c = r * 256 + tid;
      int row = c >> 3, g = c & 7;
      int kel = k0 + ((g ^ (row & 7)) << 3);
      gld16(Ab + (size_t)row * K + kel, (char*)lA + c * 16);
      gld16(Bb + (size_t)row * K + kel, (char*)lB + c * 16);
    }
    __syncthreads();
#pragma unroll
    for (int kk = 0; kk < 2; ++kk) {
      bf16x8 av[4], bv[4];
      int kbyte = (kk * 32 + lk * 8) * 2;
#pragma unroll
      for (int m = 0; m < 4; ++m) {
        int row = wr * 64 + m * 16 + lrow;
        int byt = (row * 128 + kbyte) ^ ((row & 7) << 4);
        av[m] = *(const bf16x8*)((const char*)lA + byt);
      }
#pragma unroll
      for (int n = 0; n < 4; ++n) {
        int row = wc * 64 + n * 16 + lrow;
        int byt = (row * 128 + kbyte) ^ ((row & 7) << 4);
        bv[n] = *(const bf16x8*)((const char*)lB + byt);
      }
#pragma unroll
      for (int m = 0; m < 4; ++m)
#pragma unroll
        for (int n = 0; n < 4; ++n)
          acc[m][n] = __builtin_amdgcn_mfma_f32_16x16x32_bf16(av[m], bv[n], acc[m][n], 0, 0, 0);
    }
    __syncthreads();
  }

  int grow0 = blockIdx.y * 128 + wr * 64 + lk * 4;
  int gcol0 = blockIdx.x * 128 + wc * 64 + lrow;
#pragma unroll
  for (int m = 0; m < 4; ++m)
#pragma unroll
    for (int n = 0; n < 4; ++n)
#pragma unroll
      for (int r = 0; r < 4; ++r) {
        size_t off = (size_t)(grow0 + m * 16 + r) * ldC + gcol0 + n * 16;
        if (EPI == 0) Cf[off] = acc[m][n][r];
        else if (EPI == 1) Cb[off] = f2bf(acc[m][n][r]);
        else Cf[off] += acc[m][n][r];
      }
}

// ------------- fused per-head RMS+RoPE (Q,K) + V scatter ---------------------
// grid (T, 32): z<16 -> Q head z ; 16<=z<24 -> K head z-16 ; else V head z-24
__global__ void rope_k(const float* __restrict__ qkvf, const float* __restrict__ wq,
                       const float* __restrict__ wk,
                       const float* __restrict__ cosT, const float* __restrict__ sinT,
                       const int* __restrict__ plp,
                       u16* __restrict__ qr, u16* __restrict__ kr,
                       u16* __restrict__ vTb, float* __restrict__ key_out,
                       float* __restrict__ val_out)
{
  int t = blockIdx.x, z = blockIdx.y, l = threadIdx.x;
  int p = plp[0] + t;
  const float* row = qkvf + (size_t)t * 4096;
  if (z < 24) {
    int h = z < 16 ? z : (z - 16);
    int coff = z < 16 ? h * DH_ : 2048 + h * DH_;
    const float* wn = z < 16 ? wq : wk;
    float x1 = row[coff + l], x2 = row[coff + l + 64];
    float ss = x1 * x1 + x2 * x2;
#pragma unroll
    for (int m = 32; m; m >>= 1) ss += __shfl_xor(ss, m);
    float inv = rsqrtf(ss * (1.f / DH_) + EPS_);
    float xn1 = wn[l] * x1 * inv, xn2 = wn[l + 64] * x2 * inv;
    float r1 = xn1 * cosT[(size_t)p * DH_ + l]      - xn2 * sinT[(size_t)p * DH_ + l];
    float r2 = xn2 * cosT[(size_t)p * DH_ + l + 64] + xn1 * sinT[(size_t)p * DH_ + l + 64];
    size_t o = ((size_t)h * T_ + t) * DH_;
    if (z < 16) {
      qr[o + l] = f2bf(r1); qr[o + l + 64] = f2bf(r2);
    } else {
      kr[o + l] = f2bf(r1); kr[o + l + 64] = f2bf(r2);
      key_out[((size_t)h * DH_ + l) * SMAX_ + p] = r1;
      key_out[((size_t)h * DH_ + l + 64) * SMAX_ + p] = r2;
    }
  } else {
    int kv = z - 24;
    float v1 = row[3072 + kv * DH_ + l], v2 = row[3072 + kv * DH_ + l + 64];
    vTb[((size_t)kv * DH_ + l) * T_ + t] = f2bf(v1);
    vTb[((size_t)kv * DH_ + l + 64) * T_ + t] = f2bf(v2);
    val_out[((size_t)kv * SMAX_ + p) * DH_ + l] = v1;
    val_out[((size_t)kv * SMAX_ + p) * DH_ + l + 64] = v2;
  }
}

// ---------------- flash attention: per (q-tile of 64, head) ------------------
// S^T = mfma(K,Q) -> per-t softmax is in-lane + 2 shfl_xor; P through swizzled
// LDS; V shares K's LDS buffer. acc_o rows t, cols d.
__global__ __launch_bounds__(256)
void flash_k(const u16* __restrict__ qr, const u16* __restrict__ kr,
             const u16* __restrict__ vTb, const float* __restrict__ am,
             const int* __restrict__ plp, u16* __restrict__ ctx)
{
  __shared__ u16 lQ[QB * DH_];    // 16 KB
  __shared__ u16 lKV[SB * DH_];   // 32 KB (K tile, then V tile)
  __shared__ u16 lP[QB * SB];     // 16 KB
  __shared__ float lScale[QB];
  __shared__ float lSum[QB];

  int qt = blockIdx.x, h = blockIdx.y;
  int kvh = h >> 1;
  int pl = plp[0];
  int tid = threadIdx.x;
  int l = tid & 63, w = tid >> 6;
  int lrow = l & 15, lk = l >> 4;

  const u16* Qb = qr + ((size_t)h * T_ + qt * QB) * DH_;
  const u16* Kb = kr + (size_t)kvh * T_ * DH_;
  const u16* Vb = vTb + (size_t)kvh * DH_ * T_;

  // stage Q (64 rows x 128): 1024 16B-units
#pragma unroll
  for (int r = 0; r < 4; ++r) {
    int c = r * 256 + tid;
    int row = c >> 4, g = c & 15;
    gld16(Qb + (size_t)row * DH_ + ((g ^ (row & 7)) << 3), (char*)lQ + c * 16);
  }

  float m_run = -3.0e38f, l_run = 0.f;
  f32x4 acc_o[4][2] = {};   // row t = m*16+lk*4+r ; col d = w*32+n*16+lrow

  int t_lo = qt * QB;
  int s_hi = min(T_, t_lo + QB + pl);
  int nt = (s_hi + SB - 1) / SB;
  int tcol = w * 16 + lrow;        // local t this lane owns for softmax
  int tg = t_lo + tcol;

  for (int it = 0; it < nt; ++it) {
    int s0 = it * SB;
    // stage K tile (128 rows x 128): 2048 units
#pragma unroll
    for (int r = 0; r < 8; ++r) {
      int c = r * 256 + tid;
      int row = c >> 4, g = c & 15;
      gld16(Kb + (size_t)(s0 + row) * DH_ + ((g ^ (row & 7)) << 3), (char*)lKV + c * 16);
    }
    __syncthreads();

    // S^T: C[s][t], M=128, N=64; wave owns 16 t-cols
    f32x4 acc_s[8] = {};
#pragma unroll
    for (int kk = 0; kk < 4; ++kk) {
      int kbyte = kk * 64 + lk * 16;
      int trow = w * 16 + lrow;
      bf16x8 bq = *(const bf16x8*)((const char*)lQ + ((trow * 256 + kbyte) ^ ((trow & 7) << 4)));
#pragma unroll
      for (int m = 0; m < 8; ++m) {
        int srow = m * 16 + lrow;
        bf16x8 ak = *(const bf16x8*)((const char*)lKV + ((srow * 256 + kbyte) ^ ((srow & 7) << 4)));
        acc_s[m] = __builtin_amdgcn_mfma_f32_16x16x32_bf16(ak, bq, acc_s[m], 0, 0, 0);
      }
    }
    __syncthreads();   // all waves done reading K

    // stage V tile (128 d-rows x 128 s-cols) into lKV; overlaps softmax below
#pragma unroll
    for (int r = 0; r < 8; ++r) {
      int c = r * 256 + tid;
      int row = c >> 4, g = c & 15;
      gld16(Vb + (size_t)row * T_ + s0 + ((g ^ (row & 7)) << 3), (char*)lKV + c * 16);
    }

    // mask + online softmax (per lane: one t-col, 32 s-vals)
    bool full = (s0 + SB <= t_lo + pl + 1);
    float vmax = -3.0e38f;
    float sv[8][4];
    if (full) {
#pragma unroll
      for (int m = 0; m < 8; ++m)
#pragma unroll
        for (int r = 0; r < 4; ++r) {
          float val = acc_s[m][r]; sv[m][r] = val; vmax = fmaxf(vmax, val);
        }
    } else {
#pragma unroll
      for (int m = 0; m < 8; ++m) {
        int sg = s0 + m * 16 + lk * 4;
        fvec4 a4 = *(const fvec4*)(am + (size_t)tg * T_ + sg);
#pragma unroll
        for (int r = 0; r < 4; ++r) {
          float val = acc_s[m][r] + ((sg + r <= tg + pl) ? 0.f : -128.f * a4[r]);
          sv[m][r] = val; vmax = fmaxf(vmax, val);
        }
      }
    }
    vmax = fmaxf(vmax, __shfl_xor(vmax, 16));
    vmax = fmaxf(vmax, __shfl_xor(vmax, 32));
    float m_new = fmaxf(m_run, vmax);
    float corr = __expf(m_run - m_new);
    float psum = 0.f;
    u32 pw[8][2];
#pragma unroll
    for (int m = 0; m < 8; ++m) {
      float p0 = __expf(sv[m][0] - m_new);
      float p1 = __expf(sv[m][1] - m_new);
      float p2 = __expf(sv[m][2] - m_new);
      float p3 = __expf(sv[m][3] - m_new);
      psum += (p0 + p1) + (p2 + p3);
      pw[m][0] = (u32)f2bf(p0) | ((u32)f2bf(p1) << 16);
      pw[m][1] = (u32)f2bf(p2) | ((u32)f2bf(p3) << 16);
    }
    psum += __shfl_xor(psum, 16);
    psum += __shfl_xor(psum, 32);
    l_run = l_run * corr + psum;
    m_run = m_new;
    if (lk == 0) lScale[tcol] = corr;
    // write P[t][s] bf16, XOR-swizzled rows
#pragma unroll
    for (int m = 0; m < 8; ++m) {
      int byt = (tcol * 256 + m * 32 + lk * 8) ^ ((tcol & 7) << 4);
      *(uint2*)((char*)lP + byt) = make_uint2(pw[m][0], pw[m][1]);
    }
    __syncthreads();   // V staged + P/scale visible

    // rescale O by corr[t]
#pragma unroll
    for (int m = 0; m < 4; ++m) {
      fvec4 c4 = *(const fvec4*)&lScale[m * 16 + lk * 4];
#pragma unroll
      for (int n = 0; n < 2; ++n)
#pragma unroll
        for (int r = 0; r < 4; ++r) acc_o[m][n][r] *= c4[r];
    }
    // PV: C[t][d] += P(t,s) . V^T(d,s)
#pragma unroll
    for (int kk = 0; kk < 4; ++kk) {
      int kbyte = kk * 64 + lk * 16;
      bf16x8 ap[4], bv[2];
#pragma unroll
      for (int m = 0; m < 4; ++m) {
        int trow = m * 16 + lrow;
        ap[m] = *(const bf16x8*)((const char*)lP + ((trow * 256 + kbyte) ^ ((trow & 7) << 4)));
      }
#pragma unroll
      for (int n = 0; n < 2; ++n) {
        int drow = w * 32 + n * 16 + lrow;
        bv[n] = *(const bf16x8*)((const char*)lKV + ((drow * 256 + kbyte) ^ ((drow & 7) << 4)));
      }
#pragma unroll
      for (int m = 0; m < 4; ++m)
#pragma unroll
        for (int n = 0; n < 2; ++n)
          acc_o[m][n] = __builtin_amdgcn_mfma_f32_16x16x32_bf16(ap[m], bv[n], acc_o[m][n], 0, 0, 0);
    }
    __syncthreads();   // reads of lP/lKV done before next K stage
  }

  if (lk == 0) lSum[tcol] = l_run;
  __syncthreads();
#pragma unroll
  for (int m = 0; m < 4; ++m) {
    fvec4 s4 = *(const fvec4*)&lSum[m * 16 + lk * 4];
#pragma unroll
    for (int r = 0; r < 4; ++r) {
      float inv = 1.f / s4[r];
      int trow = t_lo + m * 16 + lk * 4 + r;
      u16* crow = ctx + (size_t)trow * (H_ * DH_) + h * DH_;
#pragma unroll
      for (int n = 0; n < 2; ++n) {
        int d = w * 32 + n * 16 + lrow;
        crow[d] = f2bf(acc_o[m][n][r] * inv);
      }
    }
  }
}

// ---------------- silu(gate)*up from merged bf16 buffer ----------------------
__global__ void silu_k(const u16* __restrict__ gu, u16* __restrict__ o)
{
  int t = blockIdx.y;
  int f0 = (blockIdx.x * 256 + threadIdx.x) * 8;
  const u16* gp = gu + (size_t)t * 12288 + f0;
  union { u16 h[8]; uint4 q; } g, u, r;
  g.q = *(const uint4*)gp;
  u.q = *(const uint4*)(gp + 6144);
#pragma unroll
  for (int j = 0; j < 8; ++j) {
    float gx = bf2f(g.h[j]), ux = bf2f(u.h[j]);
    r.h[j] = f2bf(gx / (1.f + __expf(-gx)) * ux);
  }
  *(uint4*)(o + (size_t)t * 6144 + f0) = r.q;
}

// ---------------- final RMS (last token) -------------------------------------
__global__ void frms_k(const float* __restrict__ x, const float* __restrict__ w,
                       float* __restrict__ out)
{
  __shared__ float sm[4];
  float s = 0.f;
  for (int d = threadIdx.x; d < D_; d += 256) { float v = x[d]; s += v * v; }
  s = blk_sum(s, sm);
  float inv = rsqrtf(s * (1.f / D_) + EPS_);
  for (int d = threadIdx.x; d < D_; d += 256) out[d] = w[d] * x[d] * inv;
}

// ---------------- LM head partial GEMV (f32) ---------------------------------
__global__ void lmgemv_k(const float* __restrict__ last, const float* __restrict__ Wlm,
                         float* __restrict__ part)
{
  __shared__ float ls[256];
  int v = blockIdx.x * 256 + threadIdx.x;
  int c = blockIdx.y;
  ls[threadIdx.x] = last[c * 256 + threadIdx.x];
  __syncthreads();
  const float* Wp = Wlm + (size_t)c * 256 * V_ + v;
  float acc = 0.f;
#pragma unroll 8
  for (int d = 0; d < 256; d++) acc += ls[d] * Wp[(size_t)d * V_];
  part[(size_t)c * V_ + v] = acc;
}

__global__ void amax_part_k(const float* __restrict__ part, float2* __restrict__ out)
{
  __shared__ float sv[4];
  __shared__ int si[4];
  int v = blockIdx.x * 256 + threadIdx.x;
  float val = 0.f;
#pragma unroll
  for (int c = 0; c < 8; c++) val += part[(size_t)c * V_ + v];
  float bv = val; int bi = v;
#pragma unroll
  for (int m = 32; m; m >>= 1) {
    float ov = __shfl_xor(bv, m);
    int oi = __shfl_xor(bi, m);
    if (ov > bv || (ov == bv && oi < bi)) { bv = ov; bi = oi; }
  }
  if ((threadIdx.x & 63) == 0) { sv[threadIdx.x >> 6] = bv; si[threadIdx.x >> 6] = bi; }
  __syncthreads();
  if (threadIdx.x == 0) {
    for (int w = 1; w < 4; w++)
      if (sv[w] > bv || (sv[w] == bv && si[w] < bi)) { bv = sv[w]; bi = si[w]; }
    out[blockIdx.x] = make_float2(bv, (float)bi);
  }
}

__global__ void finalize_k(const float2* __restrict__ part, int np,
                           const int* __restrict__ plp, float* __restrict__ dout,
                           unsigned long long lastoff)
{
  if (threadIdx.x == 0) {
    float bv = part[0].x; int bi = (int)part[0].y;
    for (int b = 1; b < np; b++) {
      float v = part[b].x; int i = (int)part[b].y;
      if (v > bv || (v == bv && i < bi)) { bv = v; bi = i; }
    }
    dout[0] = (float)bi;
    dout[lastoff] = (float)(plp[0] + T_);
  }
}

// =============================================================================
extern "C" void kernel_launch(void* const* d_in, const int* in_sizes, int n_in,
                              void* d_out, int out_size, void* d_ws, size_t ws_size,
                              hipStream_t stream)
{
  (void)in_sizes; (void)n_in; (void)out_size; (void)ws_size;

  const float* key_in  = (const float*)d_in[0];
  const float* val_in  = (const float*)d_in[1];
  const int*   ids     = (const int*)d_in[2];
  const float* am      = (const float*)d_in[3];
  const int*   plp     = (const int*)d_in[4];
  const void*  edata   = d_in[5];
  const float* esc     = (const float*)d_in[6];
  const float* ez      = (const float*)d_in[7];
  const float* cosT    = (const float*)d_in[8];
  const float* sinT    = (const float*)d_in[9];
  const float* w_in_ln = (const float*)d_in[10];
  const float* Wq      = (const float*)d_in[11];
  const float* Wk      = (const float*)d_in[12];
  const float* Wv      = (const float*)d_in[13];
  const float* wqn     = (const float*)d_in[14];
  const float* wkn     = (const float*)d_in[15];
  const float* Wo      = (const float*)d_in[16];
  const float* wpost   = (const float*)d_in[17];
  const float* Wg      = (const float*)d_in[18];
  const float* Wu      = (const float*)d_in[19];
  const float* Wd      = (const float*)d_in[20];
  const float* wfin    = (const float*)d_in[21];
  const float* Wlm     = (const float*)d_in[22];

  float* out = (float*)d_out;
  const size_t KVN = (size_t)L_ * KVH_ * DH_ * SMAX_; // 8388608
  float* key_out = out + 1;
  float* val_out = out + 1 + KVN;
  unsigned long long lastoff = 1 + 2 * KVN;

  char* ws = (char*)d_ws;
  u16*   wT     = (u16*)  (ws + 0);            // 50,331,648
  u16*   hn     = (u16*)  (ws + 50331648);     //  4,194,304
  float* qkvf   = (float*)(ws + 54525952);     // 16,777,216
  u16*   qr     = (u16*)  (ws + 71303168);     //  4,194,304
  u16*   kr     = (u16*)  (ws + 75497472);     //  2,097,152
  u16*   vT     = (u16*)  (ws + 77594624);     //  2,097,152
  u16*   ctx    = (u16*)  (ws + 79691776);     //  4,194,304
  float* hidden = (float*)(ws + 83886080);     //  8,388,608
  u16*   gu     = (u16*)  (ws + 92274688);     // 25,165,824
  u16*   mlp    = (u16*)  (ws + 117440512);    // 12,582,912
  float* last   = (float*)(ws + 130023424);    //      8,192
  float* lpart  = (float*)(ws + 130031616);    //  1,024,000
  float2* amaxp = (float2*)(ws + 131055616);   //      4,096

  hipMemcpyAsync(key_out, key_in, KVN * sizeof(float), hipMemcpyDeviceToDevice, stream);
  hipMemcpyAsync(val_out, val_in, KVN * sizeof(float), hipMemcpyDeviceToDevice, stream);
  embed_k<<<T_, 256, 0, stream>>>(ids, edata, esc, ez, hidden);

  for (int i = 0; i < L_; i++) {
    // --- attention ---
    rms_k<<<T_, 256, 0, stream>>>(hidden, w_in_ln + (size_t)i * D_, hn);
    convT_k<<<dim3(32, 32), 256, 0, stream>>>(Wq + (size_t)i * 4194304, wT, 2048, 2048);
    convT_k<<<dim3(16, 32), 256, 0, stream>>>(Wk + (size_t)i * 2097152, wT + (size_t)2048 * 2048, 2048, 1024);
    convT_k<<<dim3(16, 32), 256, 0, stream>>>(Wv + (size_t)i * 2097152, wT + (size_t)3072 * 2048, 2048, 1024);
    gemm_bt<0><<<dim3(32, 8), 256, 0, stream>>>(hn, wT, qkvf, nullptr, 2048, 4096);
    rope_k<<<dim3(T_, 32), 64, 0, stream>>>(qkvf, wqn + (size_t)i * DH_, wkn + (size_t)i * DH_,
        cosT, sinT, plp, qr, kr, vT,
        key_out + (size_t)i * KVH_ * DH_ * SMAX_,
        val_out + (size_t)i * KVH_ * SMAX_ * DH_);
    flash_k<<<dim3(T_ / QB, H_), 256, 0, stream>>>(qr, kr, vT, am, plp, ctx);
    convT_k<<<dim3(32, 32), 256, 0, stream>>>(Wo + (size_t)i * 4194304, wT, 2048, 2048);
    gemm_bt<2><<<dim3(16, 8), 256, 0, stream>>>(ctx, wT, hidden, nullptr, 2048, 2048);

    // --- MLP ---
    rms_k<<<T_, 256, 0, stream>>>(hidden, wpost + (size_t)i * D_, hn);
    convT_k<<<dim3(96, 32), 256, 0, stream>>>(Wg + (size_t)i * 12582912, wT, 2048, 6144);
    convT_k<<<dim3(96, 32), 256, 0, stream>>>(Wu + (size_t)i * 12582912, wT + (size_t)6144 * 2048, 2048, 6144);
    gemm_bt<1><<<dim3(96, 8), 256, 0, stream>>>(hn, wT, nullptr, gu, 2048, 12288);
    silu_k<<<dim3(3, T_), 256, 0, stream>>>(gu, mlp);
    convT_k<<<dim3(32, 96), 256, 0, stream>>>(Wd + (size_t)i * 12582912, wT, 6144, 2048);
    gemm_bt<2><<<dim3(16, 8), 256, 0, stream>>>(mlp, wT, hidden, nullptr, 6144, 2048);
  }

  frms_k<<<1, 256, 0, stream>>>(hidden + (size_t)(T_ - 1) * D_, wfin, last);
  lmgemv_k<<<dim3(V_ / 256, 8), 256, 0, stream>>>(last, Wlm, lpart);
  amax_part_k<<<V_ / 256, 256, 0, stream>>>(lpart, amaxp);
  finalize_k<<<1, 64, 0, stream>>>(amaxp, V_ / 256, plp, out, lastoff);
}

// Round 3
// 1304.894 us; speedup vs baseline: 1.8554x; 1.3699x over previous
//
#include <hip/hip_runtime.h>
#include <cstdint>

#define L_ 4
#define D_ 2048
#define H_ 16
#define KVH_ 8
#define DH_ 128
#define F_ 6144
#define V_ 32000
#define SMAX_ 2048
#define T_ 1024
#define EPS_ 1e-6f
#define QB 64
#define SB 128

typedef unsigned short u16;
typedef unsigned int u32;
typedef float fvec4 __attribute__((ext_vector_type(4)));
typedef float f32x4 __attribute__((ext_vector_type(4)));
typedef __bf16 bf16x8 __attribute__((ext_vector_type(8)));

__device__ __forceinline__ u16 f2bf(float f) {
  union { float f; u32 u; } a; a.f = f;
  u32 u = a.u;
  return (u16)((u + 0x7FFFu + ((u >> 16) & 1u)) >> 16);
}

__device__ __forceinline__ void gld16(const void* g, void* l) {
  __builtin_amdgcn_global_load_lds(
      (const __attribute__((address_space(1))) void*)g,
      (__attribute__((address_space(3))) void*)l, 16, 0, 0);
}

__device__ __forceinline__ float blk_sum(float v, volatile float* sm) {
#pragma unroll
  for (int m = 32; m; m >>= 1) v += __shfl_xor(v, m);
  if ((threadIdx.x & 63) == 0) sm[threadIdx.x >> 6] = v;
  __syncthreads();
  v = sm[0] + sm[1] + sm[2] + sm[3];
  __syncthreads();
  return v;
}

// ---------------- embedding (uint8-vs-int32 runtime detection) ---------------
__global__ void embed_k(const int* __restrict__ ids, const void* __restrict__ edata,
                        const float* __restrict__ esc, const float* __restrict__ ez,
                        float* __restrict__ hidden)
{
  const int* ei = (const int*)edata;
  int chk = ei[threadIdx.x & 63];
  bool ok = ((unsigned)chk) <= 255u;
  bool is_i32 = (__ballot(ok) == ~0ULL);
  int t = blockIdx.x;
  int id = ids[t];
  float sc = esc[id], zp = ez[id];
  size_t base = (size_t)id * D_;
  const uint8_t* eb = (const uint8_t*)edata;
  for (int d = threadIdx.x; d < D_; d += 256) {
    float e = is_i32 ? (float)ei[base + d] : (float)eb[base + d];
    hidden[(size_t)t * D_ + d] = e * sc + zp;
  }
}

// ------ convT v2: up to 3 segments, fvec4 loads, [64][65] f32 LDS ------------
// gu=1 remaps output rows for gate/up 16-col interleave: row = rb + (f>>4)*32 + (f&15)
__global__ __launch_bounds__(256)
void convT2_k(const float* __restrict__ W0, const float* __restrict__ W1,
              const float* __restrict__ W2,
              int x1, int x2, int N0, int N1, int N2,
              int r0, int r1, int r2, int K, u16* __restrict__ WT, int gu)
{
  __shared__ float tile[64][65];
  int x = blockIdx.x, k0 = blockIdx.y * 64;
  const float* W; int N, nb, rb;
  if (x < x1)      { W = W0; N = N0; nb = x;      rb = r0; }
  else if (x < x2) { W = W1; N = N1; nb = x - x1; rb = r1; }
  else             { W = W2; N = N2; nb = x - x2; rb = r2; }
  int n0 = nb * 64;
  int tid = threadIdx.x;
  int lk = tid >> 4, n4 = (tid & 15) * 4;
#pragma unroll
  for (int i = 0; i < 4; ++i) {
    int kr = i * 16 + lk;
    fvec4 v = *(const fvec4*)(W + (size_t)(k0 + kr) * N + n0 + n4);
#pragma unroll
    for (int j = 0; j < 4; ++j) tile[n4 + j][kr] = v[j];
  }
  __syncthreads();
  int n = tid >> 2, kq = (tid & 3) * 16;
  int f = n0 + n;
  int row = gu ? (rb + ((f >> 4) << 5) + (f & 15)) : (rb + f);
  union { u16 h[16]; uint4 q[2]; } o;
#pragma unroll
  for (int i = 0; i < 16; ++i) o.h[i] = f2bf(tile[n][kq + i]);
  u16* op = WT + (size_t)row * K + k0 + kq;
  *(uint4*)op = o.q[0];
  *(uint4*)(op + 8) = o.q[1];
}

// ---------------- RMS norm f32 -> bf16; COMB=1: x += p0+p1 first -------------
template<int COMB>
__global__ void rms_k(float* __restrict__ x, const float* __restrict__ p0,
                      const float* __restrict__ p1, const float* __restrict__ w,
                      u16* __restrict__ out)
{
  __shared__ float sm[4];
  int t = blockIdx.x;
  fvec4* xr = (fvec4*)(x + (size_t)t * D_);
  fvec4 v0 = xr[threadIdx.x], v1 = xr[threadIdx.x + 256];
  if (COMB) {
    const fvec4* a = (const fvec4*)(p0 + (size_t)t * D_);
    const fvec4* b = (const fvec4*)(p1 + (size_t)t * D_);
    v0 += a[threadIdx.x] + b[threadIdx.x];
    v1 += a[threadIdx.x + 256] + b[threadIdx.x + 256];
    xr[threadIdx.x] = v0;
    xr[threadIdx.x + 256] = v1;
  }
  float s = v0[0]*v0[0] + v0[1]*v0[1] + v0[2]*v0[2] + v0[3]*v0[3]
          + v1[0]*v1[0] + v1[1]*v1[1] + v1[2]*v1[2] + v1[3]*v1[3];
  s = blk_sum(s, sm);
  float inv = rsqrtf(s * (1.f / D_) + EPS_);
  const fvec4* wr = (const fvec4*)w;
  fvec4 w0 = wr[threadIdx.x], w1 = wr[threadIdx.x + 256];
  u16* orow = out + (size_t)t * D_;
  uint2 o0, o1;
  o0.x = (u32)f2bf(w0[0]*v0[0]*inv) | ((u32)f2bf(w0[1]*v0[1]*inv) << 16);
  o0.y = (u32)f2bf(w0[2]*v0[2]*inv) | ((u32)f2bf(w0[3]*v0[3]*inv) << 16);
  o1.x = (u32)f2bf(w1[0]*v1[0]*inv) | ((u32)f2bf(w1[1]*v1[1]*inv) << 16);
  o1.y = (u32)f2bf(w1[2]*v1[2]*inv) | ((u32)f2bf(w1[3]*v1[3]*inv) << 16);
  *(uint2*)(orow + threadIdx.x * 4) = o0;
  *(uint2*)(orow + (threadIdx.x + 256) * 4) = o1;
}

// -------- GEMM: C(MxN)=A(MxK)*B^T(NxK) bf16, split-K via blockIdx.z ----------
// EPI 0: Cf[z]=acc (partial)  EPI 2: Cf+=acc  EPI 3: silu-pair -> Cb bf16
template<int EPI>
__global__ __launch_bounds__(256)
void gemm_bt(const u16* __restrict__ A, const u16* __restrict__ B,
             float* __restrict__ Cf, u16* __restrict__ Cb,
             int K, int Ks, int ldC, long long zStride)
{
  __shared__ u16 lA[128 * 64];
  __shared__ u16 lB[128 * 64];
  const u16* Ab = A + (size_t)blockIdx.y * 128 * K;
  const u16* Bb = B + (size_t)blockIdx.x * 128 * K;
  int kz = blockIdx.z * Ks;

  int tid = threadIdx.x;
  int l = tid & 63;
  int wid = tid >> 6;
  int wr = wid >> 1, wc = wid & 1;
  int lrow = l & 15, lk = l >> 4;

  f32x4 acc[4][4] = {};

  for (int k0 = 0; k0 < Ks; k0 += 64) {
#pragma unroll
    for (int r = 0; r < 4; ++r) {
      int c = r * 256 + tid;
      int row = c >> 3, g = c & 7;
      int kel = kz + k0 + ((g ^ (row & 7)) << 3);
      gld16(Ab + (size_t)row * K + kel, (char*)lA + c * 16);
      gld16(Bb + (size_t)row * K + kel, (char*)lB + c * 16);
    }
    __syncthreads();
#pragma unroll
    for (int kk = 0; kk < 2; ++kk) {
      bf16x8 av[4], bv[4];
      int kbyte = (kk * 32 + lk * 8) * 2;
#pragma unroll
      for (int m = 0; m < 4; ++m) {
        int row = wr * 64 + m * 16 + lrow;
        int byt = (row * 128 + kbyte) ^ ((row & 7) << 4);
        av[m] = *(const bf16x8*)((const char*)lA + byt);
      }
#pragma unroll
      for (int n = 0; n < 4; ++n) {
        int row = wc * 64 + n * 16 + lrow;
        int byt = (row * 128 + kbyte) ^ ((row & 7) << 4);
        bv[n] = *(const bf16x8*)((const char*)lB + byt);
      }
#pragma unroll
      for (int m = 0; m < 4; ++m)
#pragma unroll
        for (int n = 0; n < 4; ++n)
          acc[m][n] = __builtin_amdgcn_mfma_f32_16x16x32_bf16(av[m], bv[n], acc[m][n], 0, 0, 0);
    }
    __syncthreads();
  }

  int grow0 = blockIdx.y * 128 + wr * 64 + lk * 4;
  if (EPI == 3) {
    int fcol0 = blockIdx.x * 64 + wc * 32 + lrow;
#pragma unroll
    for (int m = 0; m < 4; ++m)
#pragma unroll
      for (int np = 0; np < 2; ++np)
#pragma unroll
        for (int r = 0; r < 4; ++r) {
          float g = acc[m][2 * np][r], u = acc[m][2 * np + 1][r];
          float val = g / (1.f + __expf(-g)) * u;
          Cb[(size_t)(grow0 + m * 16 + r) * ldC + fcol0 + np * 16] = f2bf(val);
        }
    return;
  }
  float* Cz = Cf + (long long)blockIdx.z * zStride;
  int gcol0 = blockIdx.x * 128 + wc * 64 + lrow;
#pragma unroll
  for (int m = 0; m < 4; ++m)
#pragma unroll
    for (int n = 0; n < 4; ++n)
#pragma unroll
      for (int r = 0; r < 4; ++r) {
        size_t off = (size_t)(grow0 + m * 16 + r) * ldC + gcol0 + n * 16;
        if (EPI == 0) Cz[off] = acc[m][n][r];
        else Cz[off] += acc[m][n][r];
      }
}

// ------------- per-(t,head) RMS+RoPE for Q,K from split-K partials -----------
// grid (T, 24): z<16 Q head z ; else K head z-16
__global__ void rope_k(const float* __restrict__ p0, const float* __restrict__ p1,
                       const float* __restrict__ wq, const float* __restrict__ wk,
                       const float* __restrict__ cosT, const float* __restrict__ sinT,
                       const int* __restrict__ plp,
                       u16* __restrict__ qr, u16* __restrict__ kr,
                       float* __restrict__ key_out)
{
  int t = blockIdx.x, z = blockIdx.y, l = threadIdx.x;
  int p = plp[0] + t;
  int h = z < 16 ? z : (z - 16);
  int coff = z < 16 ? h * DH_ : 2048 + h * DH_;
  const float* wn = z < 16 ? wq : wk;
  size_t base = (size_t)t * 4096 + coff;
  float x1 = p0[base + l] + p1[base + l];
  float x2 = p0[base + l + 64] + p1[base + l + 64];
  float ss = x1 * x1 + x2 * x2;
#pragma unroll
  for (int m = 32; m; m >>= 1) ss += __shfl_xor(ss, m);
  float inv = rsqrtf(ss * (1.f / DH_) + EPS_);
  float xn1 = wn[l] * x1 * inv, xn2 = wn[l + 64] * x2 * inv;
  float r1 = xn1 * cosT[(size_t)p * DH_ + l]      - xn2 * sinT[(size_t)p * DH_ + l];
  float r2 = xn2 * cosT[(size_t)p * DH_ + l + 64] + xn1 * sinT[(size_t)p * DH_ + l + 64];
  size_t o = ((size_t)h * T_ + t) * DH_;
  if (z < 16) {
    qr[o + l] = f2bf(r1); qr[o + l + 64] = f2bf(r2);
  } else {
    kr[o + l] = f2bf(r1); kr[o + l + 64] = f2bf(r2);
    key_out[((size_t)h * DH_ + l) * SMAX_ + p] = r1;
    key_out[((size_t)h * DH_ + l + 64) * SMAX_ + p] = r2;
  }
}

// -------- V tile: partials -> val_out (f32, coalesced) + vT bf16 [kv][d][t] --
__global__ __launch_bounds__(256)
void vtile_k(const float* __restrict__ p0, const float* __restrict__ p1,
             const int* __restrict__ plp, u16* __restrict__ vT,
             float* __restrict__ vout)
{
  __shared__ float tile[64][65];
  int t0 = blockIdx.x * 64, kv = blockIdx.y;
  int pl = plp[0];
  int tid = threadIdx.x;
  for (int dh = 0; dh < 2; ++dh) {
    int d0 = dh * 64;
    int tt = tid >> 4, d4 = (tid & 15) * 4;
#pragma unroll
    for (int i = 0; i < 4; ++i) {
      int tr = i * 16 + tt;
      size_t off = (size_t)(t0 + tr) * 4096 + 3072 + kv * DH_ + d0 + d4;
      fvec4 v = *(const fvec4*)(p0 + off);
      fvec4 w = *(const fvec4*)(p1 + off);
      v += w;
#pragma unroll
      for (int j = 0; j < 4; ++j) tile[d4 + j][tr] = v[j];
      *(fvec4*)(vout + ((size_t)kv * SMAX_ + pl + t0 + tr) * DH_ + d0 + d4) = v;
    }
    __syncthreads();
    int d = tid >> 2, tq = (tid & 3) * 16;
    union { u16 h[16]; uint4 q[2]; } o;
#pragma unroll
    for (int i = 0; i < 16; ++i) o.h[i] = f2bf(tile[d][tq + i]);
    u16* op = vT + ((size_t)kv * DH_ + d0 + d) * T_ + t0 + tq;
    *(uint4*)op = o.q[0];
    *(uint4*)(op + 8) = o.q[1];
    __syncthreads();
  }
}

// ---------------- flash attention: per (q-tile of 64, head) ------------------
__global__ __launch_bounds__(256)
void flash_k(const u16* __restrict__ qr, const u16* __restrict__ kr,
             const u16* __restrict__ vTb, const float* __restrict__ am,
             const int* __restrict__ plp, u16* __restrict__ ctx)
{
  __shared__ u16 lQ[QB * DH_];
  __shared__ u16 lKV[SB * DH_];
  __shared__ u16 lP[QB * SB];
  __shared__ float lScale[QB];
  __shared__ float lSum[QB];

  int qt = blockIdx.x, h = blockIdx.y;
  int kvh = h >> 1;
  int pl = plp[0];
  int tid = threadIdx.x;
  int l = tid & 63, w = tid >> 6;
  int lrow = l & 15, lk = l >> 4;

  const u16* Qb = qr + ((size_t)h * T_ + qt * QB) * DH_;
  const u16* Kb = kr + (size_t)kvh * T_ * DH_;
  const u16* Vb = vTb + (size_t)kvh * DH_ * T_;

#pragma unroll
  for (int r = 0; r < 4; ++r) {
    int c = r * 256 + tid;
    int row = c >> 4, g = c & 15;
    gld16(Qb + (size_t)row * DH_ + ((g ^ (row & 7)) << 3), (char*)lQ + c * 16);
  }

  float m_run = -3.0e38f, l_run = 0.f;
  f32x4 acc_o[4][2] = {};

  int t_lo = qt * QB;
  int s_hi = min(T_, t_lo + QB + pl);
  int nt = (s_hi + SB - 1) / SB;
  int tcol = w * 16 + lrow;
  int tg = t_lo + tcol;

  for (int it = 0; it < nt; ++it) {
    int s0 = it * SB;
#pragma unroll
    for (int r = 0; r < 8; ++r) {
      int c = r * 256 + tid;
      int row = c >> 4, g = c & 15;
      gld16(Kb + (size_t)(s0 + row) * DH_ + ((g ^ (row & 7)) << 3), (char*)lKV + c * 16);
    }
    __syncthreads();

    f32x4 acc_s[8] = {};
#pragma unroll
    for (int kk = 0; kk < 4; ++kk) {
      int kbyte = kk * 64 + lk * 16;
      int trow = w * 16 + lrow;
      bf16x8 bq = *(const bf16x8*)((const char*)lQ + ((trow * 256 + kbyte) ^ ((trow & 7) << 4)));
#pragma unroll
      for (int m = 0; m < 8; ++m) {
        int srow = m * 16 + lrow;
        bf16x8 ak = *(const bf16x8*)((const char*)lKV + ((srow * 256 + kbyte) ^ ((srow & 7) << 4)));
        acc_s[m] = __builtin_amdgcn_mfma_f32_16x16x32_bf16(ak, bq, acc_s[m], 0, 0, 0);
      }
    }
    __syncthreads();

#pragma unroll
    for (int r = 0; r < 8; ++r) {
      int c = r * 256 + tid;
      int row = c >> 4, g = c & 15;
      gld16(Vb + (size_t)row * T_ + s0 + ((g ^ (row & 7)) << 3), (char*)lKV + c * 16);
    }

    bool full = (s0 + SB <= t_lo + pl + 1);
    float vmax = -3.0e38f;
    float sv[8][4];
    if (full) {
#pragma unroll
      for (int m = 0; m < 8; ++m)
#pragma unroll
        for (int r = 0; r < 4; ++r) {
          float val = acc_s[m][r]; sv[m][r] = val; vmax = fmaxf(vmax, val);
        }
    } else {
#pragma unroll
      for (int m = 0; m < 8; ++m) {
        int sg = s0 + m * 16 + lk * 4;
        fvec4 a4 = *(const fvec4*)(am + (size_t)tg * T_ + sg);
#pragma unroll
        for (int r = 0; r < 4; ++r) {
          float val = acc_s[m][r] + ((sg + r <= tg + pl) ? 0.f : -128.f * a4[r]);
          sv[m][r] = val; vmax = fmaxf(vmax, val);
        }
      }
    }
    vmax = fmaxf(vmax, __shfl_xor(vmax, 16));
    vmax = fmaxf(vmax, __shfl_xor(vmax, 32));
    float m_new = fmaxf(m_run, vmax);
    float corr = __expf(m_run - m_new);
    float psum = 0.f;
    u32 pw[8][2];
#pragma unroll
    for (int m = 0; m < 8; ++m) {
      float pq0 = __expf(sv[m][0] - m_new);
      float pq1 = __expf(sv[m][1] - m_new);
      float pq2 = __expf(sv[m][2] - m_new);
      float pq3 = __expf(sv[m][3] - m_new);
      psum += (pq0 + pq1) + (pq2 + pq3);
      pw[m][0] = (u32)f2bf(pq0) | ((u32)f2bf(pq1) << 16);
      pw[m][1] = (u32)f2bf(pq2) | ((u32)f2bf(pq3) << 16);
    }
    psum += __shfl_xor(psum, 16);
    psum += __shfl_xor(psum, 32);
    l_run = l_run * corr + psum;
    m_run = m_new;
    if (lk == 0) lScale[tcol] = corr;
#pragma unroll
    for (int m = 0; m < 8; ++m) {
      int byt = (tcol * 256 + m * 32 + lk * 8) ^ ((tcol & 7) << 4);
      *(uint2*)((char*)lP + byt) = make_uint2(pw[m][0], pw[m][1]);
    }
    __syncthreads();

#pragma unroll
    for (int m = 0; m < 4; ++m) {
      fvec4 c4 = *(const fvec4*)&lScale[m * 16 + lk * 4];
#pragma unroll
      for (int n = 0; n < 2; ++n)
#pragma unroll
        for (int r = 0; r < 4; ++r) acc_o[m][n][r] *= c4[r];
    }
#pragma unroll
    for (int kk = 0; kk < 4; ++kk) {
      int kbyte = kk * 64 + lk * 16;
      bf16x8 ap[4], bv[2];
#pragma unroll
      for (int m = 0; m < 4; ++m) {
        int trow = m * 16 + lrow;
        ap[m] = *(const bf16x8*)((const char*)lP + ((trow * 256 + kbyte) ^ ((trow & 7) << 4)));
      }
#pragma unroll
      for (int n = 0; n < 2; ++n) {
        int drow = w * 32 + n * 16 + lrow;
        bv[n] = *(const bf16x8*)((const char*)lKV + ((drow * 256 + kbyte) ^ ((drow & 7) << 4)));
      }
#pragma unroll
      for (int m = 0; m < 4; ++m)
#pragma unroll
        for (int n = 0; n < 2; ++n)
          acc_o[m][n] = __builtin_amdgcn_mfma_f32_16x16x32_bf16(ap[m], bv[n], acc_o[m][n], 0, 0, 0);
    }
    __syncthreads();
  }

  if (lk == 0) lSum[tcol] = l_run;
  __syncthreads();
#pragma unroll
  for (int m = 0; m < 4; ++m) {
    fvec4 s4 = *(const fvec4*)&lSum[m * 16 + lk * 4];
#pragma unroll
    for (int r = 0; r < 4; ++r) {
      float inv = 1.f / s4[r];
      int trow = t_lo + m * 16 + lk * 4 + r;
      u16* crow = ctx + (size_t)trow * (H_ * DH_) + h * DH_;
#pragma unroll
      for (int n = 0; n < 2; ++n) {
        int d = w * 32 + n * 16 + lrow;
        crow[d] = f2bf(acc_o[m][n][r] * inv);
      }
    }
  }
}

// ---------------- final RMS (last token) + partial combine -------------------
__global__ void frms_k(const float* __restrict__ x, const float* __restrict__ p0,
                       const float* __restrict__ p1, const float* __restrict__ w,
                       float* __restrict__ out)
{
  __shared__ float sm[4];
  float s = 0.f;
  for (int d = threadIdx.x; d < D_; d += 256) {
    float v = x[d] + p0[d] + p1[d];
    s += v * v;
  }
  s = blk_sum(s, sm);
  float inv = rsqrtf(s * (1.f / D_) + EPS_);
  for (int d = threadIdx.x; d < D_; d += 256)
    out[d] = w[d] * (x[d] + p0[d] + p1[d]) * inv;
}

// ---------------- LM head partial GEMV (f32) ---------------------------------
__global__ void lmgemv_k(const float* __restrict__ last, const float* __restrict__ Wlm,
                         float* __restrict__ part)
{
  __shared__ float ls[256];
  int v = blockIdx.x * 256 + threadIdx.x;
  int c = blockIdx.y;
  ls[threadIdx.x] = last[c * 256 + threadIdx.x];
  __syncthreads();
  const float* Wp = Wlm + (size_t)c * 256 * V_ + v;
  float acc = 0.f;
#pragma unroll 8
  for (int d = 0; d < 256; d++) acc += ls[d] * Wp[(size_t)d * V_];
  part[(size_t)c * V_ + v] = acc;
}

__global__ void amax_part_k(const float* __restrict__ part, float2* __restrict__ out)
{
  __shared__ float sv[4];
  __shared__ int si[4];
  int v = blockIdx.x * 256 + threadIdx.x;
  float val = 0.f;
#pragma unroll
  for (int c = 0; c < 8; c++) val += part[(size_t)c * V_ + v];
  float bv = val; int bi = v;
#pragma unroll
  for (int m = 32; m; m >>= 1) {
    float ov = __shfl_xor(bv, m);
    int oi = __shfl_xor(bi, m);
    if (ov > bv || (ov == bv && oi < bi)) { bv = ov; bi = oi; }
  }
  if ((threadIdx.x & 63) == 0) { sv[threadIdx.x >> 6] = bv; si[threadIdx.x >> 6] = bi; }
  __syncthreads();
  if (threadIdx.x == 0) {
    for (int w = 1; w < 4; w++)
      if (sv[w] > bv || (sv[w] == bv && si[w] < bi)) { bv = sv[w]; bi = si[w]; }
    out[blockIdx.x] = make_float2(bv, (float)bi);
  }
}

__global__ void finalize_k(const float2* __restrict__ part, int np,
                           const int* __restrict__ plp, float* __restrict__ dout,
                           unsigned long long lastoff)
{
  if (threadIdx.x == 0) {
    float bv = part[0].x; int bi = (int)part[0].y;
    for (int b = 1; b < np; b++) {
      float v = part[b].x; int i = (int)part[b].y;
      if (v > bv || (v == bv && i < bi)) { bv = v; bi = i; }
    }
    dout[0] = (float)bi;
    dout[lastoff] = (float)(plp[0] + T_);
  }
}

// =============================================================================
extern "C" void kernel_launch(void* const* d_in, const int* in_sizes, int n_in,
                              void* d_out, int out_size, void* d_ws, size_t ws_size,
                              hipStream_t stream)
{
  (void)in_sizes; (void)n_in; (void)out_size; (void)ws_size;

  const float* key_in  = (const float*)d_in[0];
  const float* val_in  = (const float*)d_in[1];
  const int*   ids     = (const int*)d_in[2];
  const float* am      = (const float*)d_in[3];
  const int*   plp     = (const int*)d_in[4];
  const void*  edata   = d_in[5];
  const float* esc     = (const float*)d_in[6];
  const float* ez      = (const float*)d_in[7];
  const float* cosT    = (const float*)d_in[8];
  const float* sinT    = (const float*)d_in[9];
  const float* w_in_ln = (const float*)d_in[10];
  const float* Wq      = (const float*)d_in[11];
  const float* Wk      = (const float*)d_in[12];
  const float* Wv      = (const float*)d_in[13];
  const float* wqn     = (const float*)d_in[14];
  const float* wkn     = (const float*)d_in[15];
  const float* Wo      = (const float*)d_in[16];
  const float* wpost   = (const float*)d_in[17];
  const float* Wg      = (const float*)d_in[18];
  const float* Wu      = (const float*)d_in[19];
  const float* Wd      = (const float*)d_in[20];
  const float* wfin    = (const float*)d_in[21];
  const float* Wlm     = (const float*)d_in[22];

  float* out = (float*)d_out;
  const size_t KVN = (size_t)L_ * KVH_ * DH_ * SMAX_; // 8388608
  float* key_out = out + 1;
  float* val_out = out + 1 + KVN;
  unsigned long long lastoff = 1 + 2 * KVN;

  char* ws = (char*)d_ws;
  u16*   wT     = (u16*)  (ws + 0);            // 50,331,648
  u16*   hn     = (u16*)  (ws + 50331648);     //  4,194,304
  float* P0     = (float*)(ws + 54525952);     // 16,777,216 (split-K partial 0)
  float* P1     = (float*)(ws + 71303168);     // 16,777,216 (split-K partial 1)
  u16*   qr     = (u16*)  (ws + 88080384);     //  4,194,304
  u16*   kr     = (u16*)  (ws + 92274688);     //  2,097,152
  u16*   vT     = (u16*)  (ws + 94371840);     //  2,097,152
  u16*   ctx    = (u16*)  (ws + 96468992);     //  4,194,304
  float* hidden = (float*)(ws + 100663296);    //  8,388,608
  u16*   mlp    = (u16*)  (ws + 109051904);    // 12,582,912
  float* last   = (float*)(ws + 121634816);    //      8,192
  float* lpart  = (float*)(ws + 121643008);    //  1,024,000
  float2* amaxp = (float2*)(ws + 122667008);   //      4,096

  const long long ZS = 4194304; // elems between P0 and P1 (16 MB / 4)

  hipMemcpyAsync(key_out, key_in, KVN * sizeof(float), hipMemcpyDeviceToDevice, stream);
  hipMemcpyAsync(val_out, val_in, KVN * sizeof(float), hipMemcpyDeviceToDevice, stream);
  embed_k<<<T_, 256, 0, stream>>>(ids, edata, esc, ez, hidden);

  for (int i = 0; i < L_; i++) {
    // --- attention ---
    if (i == 0)
      rms_k<0><<<T_, 256, 0, stream>>>(hidden, nullptr, nullptr, w_in_ln, hn);
    else
      rms_k<1><<<T_, 256, 0, stream>>>(hidden, P0, P1, w_in_ln + (size_t)i * D_, hn);

    convT2_k<<<dim3(64, 32), 256, 0, stream>>>(
        Wq + (size_t)i * 4194304, Wk + (size_t)i * 2097152, Wv + (size_t)i * 2097152,
        32, 48, 2048, 1024, 1024, 0, 2048, 3072, 2048, wT, 0);
    gemm_bt<0><<<dim3(32, 8, 2), 256, 0, stream>>>(hn, wT, P0, nullptr, 2048, 1024, 4096, ZS);

    rope_k<<<dim3(T_, 24), 64, 0, stream>>>(P0, P1, wqn + (size_t)i * DH_, wkn + (size_t)i * DH_,
        cosT, sinT, plp, qr, kr, key_out + (size_t)i * KVH_ * DH_ * SMAX_);
    vtile_k<<<dim3(16, 8), 256, 0, stream>>>(P0, P1, plp, vT,
        val_out + (size_t)i * KVH_ * SMAX_ * DH_);

    flash_k<<<dim3(T_ / QB, H_), 256, 0, stream>>>(qr, kr, vT, am, plp, ctx);

    convT2_k<<<dim3(32, 32), 256, 0, stream>>>(
        Wo + (size_t)i * 4194304, nullptr, nullptr,
        32, 64, 2048, 2048, 2048, 0, 0, 0, 2048, wT, 0);
    gemm_bt<0><<<dim3(16, 8, 2), 256, 0, stream>>>(ctx, wT, P0, nullptr, 2048, 1024, 2048, ZS);

    // --- MLP ---
    rms_k<1><<<T_, 256, 0, stream>>>(hidden, P0, P1, wpost + (size_t)i * D_, hn);

    convT2_k<<<dim3(192, 32), 256, 0, stream>>>(
        Wg + (size_t)i * 12582912, Wu + (size_t)i * 12582912, Wu + (size_t)i * 12582912,
        96, 192, 6144, 6144, 6144, 0, 16, 16, 2048, wT, 1);
    gemm_bt<3><<<dim3(96, 8, 1), 256, 0, stream>>>(hn, wT, nullptr, mlp, 2048, 2048, 6144, 0);

    convT2_k<<<dim3(32, 96), 256, 0, stream>>>(
        Wd + (size_t)i * 12582912, nullptr, nullptr,
        32, 64, 2048, 2048, 2048, 0, 0, 0, 6144, wT, 0);
    gemm_bt<0><<<dim3(16, 8, 2), 256, 0, stream>>>(mlp, wT, P0, nullptr, 6144, 3072, 2048, ZS);
  }

  frms_k<<<1, 256, 0, stream>>>(hidden + (size_t)(T_ - 1) * D_,
                                P0 + (size_t)(T_ - 1) * D_, P1 + (size_t)(T_ - 1) * D_,
                                wfin, last);
  lmgemv_k<<<dim3(V_ / 256, 8), 256, 0, stream>>>(last, Wlm, lpart);
  amax_part_k<<<V_ / 256, 256, 0, stream>>>(lpart, amaxp);
  finalize_k<<<1, 64, 0, stream>>>(amaxp, V_ / 256, plp, out, lastoff);
}

// Round 4
// 1291.345 us; speedup vs baseline: 1.8749x; 1.0105x over previous
//
#include <hip/hip_runtime.h>
#include <cstdint>

#define L_ 4
#define D_ 2048
#define H_ 16
#define KVH_ 8
#define DH_ 128
#define F_ 6144
#define V_ 32000
#define SMAX_ 2048
#define T_ 1024
#define EPS_ 1e-6f
#define QB 64
#define SB 128

typedef unsigned short u16;
typedef unsigned int u32;
typedef float fvec4 __attribute__((ext_vector_type(4)));
typedef float f32x4 __attribute__((ext_vector_type(4)));
typedef __bf16 bf16x8 __attribute__((ext_vector_type(8)));

__device__ __forceinline__ u16 f2bf(float f) {
  union { float f; u32 u; } a; a.f = f;
  u32 u = a.u;
  return (u16)((u + 0x7FFFu + ((u >> 16) & 1u)) >> 16);
}

__device__ __forceinline__ void gld16(const void* g, void* l) {
  __builtin_amdgcn_global_load_lds(
      (const __attribute__((address_space(1))) void*)g,
      (__attribute__((address_space(3))) void*)l, 16, 0, 0);
}

__device__ __forceinline__ float blk_sum(float v, volatile float* sm) {
#pragma unroll
  for (int m = 32; m; m >>= 1) v += __shfl_xor(v, m);
  if ((threadIdx.x & 63) == 0) sm[threadIdx.x >> 6] = v;
  __syncthreads();
  v = sm[0] + sm[1] + sm[2] + sm[3];
  __syncthreads();
  return v;
}

// ---------------- embedding (uint8-vs-int32 runtime detection) ---------------
__global__ void embed_k(const int* __restrict__ ids, const void* __restrict__ edata,
                        const float* __restrict__ esc, const float* __restrict__ ez,
                        float* __restrict__ hidden)
{
  const int* ei = (const int*)edata;
  int chk = ei[threadIdx.x & 63];
  bool ok = ((unsigned)chk) <= 255u;
  bool is_i32 = (__ballot(ok) == ~0ULL);
  int t = blockIdx.x;
  int id = ids[t];
  float sc = esc[id], zp = ez[id];
  size_t base = (size_t)id * D_;
  const uint8_t* eb = (const uint8_t*)edata;
  for (int d = threadIdx.x; d < D_; d += 256) {
    float e = is_i32 ? (float)ei[base + d] : (float)eb[base + d];
    hidden[(size_t)t * D_ + d] = e * sc + zp;
  }
}

// ------ convT v2: up to 3 segments, fvec4 loads, [64][65] f32 LDS ------------
// gu=1 remaps output rows for gate/up 16-col interleave: row = rb + (f>>4)*32 + (f&15)
__global__ __launch_bounds__(256)
void convT2_k(const float* __restrict__ W0, const float* __restrict__ W1,
              const float* __restrict__ W2,
              int x1, int x2, int N0, int N1, int N2,
              int r0, int r1, int r2, int K, u16* __restrict__ WT, int gu)
{
  __shared__ float tile[64][65];
  int x = blockIdx.x, k0 = blockIdx.y * 64;
  const float* W; int N, nb, rb;
  if (x < x1)      { W = W0; N = N0; nb = x;      rb = r0; }
  else if (x < x2) { W = W1; N = N1; nb = x - x1; rb = r1; }
  else             { W = W2; N = N2; nb = x - x2; rb = r2; }
  int n0 = nb * 64;
  int tid = threadIdx.x;
  int lk = tid >> 4, n4 = (tid & 15) * 4;
#pragma unroll
  for (int i = 0; i < 4; ++i) {
    int kr = i * 16 + lk;
    fvec4 v = *(const fvec4*)(W + (size_t)(k0 + kr) * N + n0 + n4);
#pragma unroll
    for (int j = 0; j < 4; ++j) tile[n4 + j][kr] = v[j];
  }
  __syncthreads();
  int n = tid >> 2, kq = (tid & 3) * 16;
  int f = n0 + n;
  int row = gu ? (rb + ((f >> 4) << 5) + (f & 15)) : (rb + f);
  union { u16 h[16]; uint4 q[2]; } o;
#pragma unroll
  for (int i = 0; i < 16; ++i) o.h[i] = f2bf(tile[n][kq + i]);
  u16* op = WT + (size_t)row * K + k0 + kq;
  *(uint4*)op = o.q[0];
  *(uint4*)(op + 8) = o.q[1];
}

// ---------------- RMS norm f32 -> bf16; COMB=1: x += p0+p1 first -------------
template<int COMB>
__global__ void rms_k(float* __restrict__ x, const float* __restrict__ p0,
                      const float* __restrict__ p1, const float* __restrict__ w,
                      u16* __restrict__ out)
{
  __shared__ float sm[4];
  int t = blockIdx.x;
  fvec4* xr = (fvec4*)(x + (size_t)t * D_);
  fvec4 v0 = xr[threadIdx.x], v1 = xr[threadIdx.x + 256];
  if (COMB) {
    const fvec4* a = (const fvec4*)(p0 + (size_t)t * D_);
    const fvec4* b = (const fvec4*)(p1 + (size_t)t * D_);
    v0 += a[threadIdx.x] + b[threadIdx.x];
    v1 += a[threadIdx.x + 256] + b[threadIdx.x + 256];
    xr[threadIdx.x] = v0;
    xr[threadIdx.x + 256] = v1;
  }
  float s = v0[0]*v0[0] + v0[1]*v0[1] + v0[2]*v0[2] + v0[3]*v0[3]
          + v1[0]*v1[0] + v1[1]*v1[1] + v1[2]*v1[2] + v1[3]*v1[3];
  s = blk_sum(s, sm);
  float inv = rsqrtf(s * (1.f / D_) + EPS_);
  const fvec4* wr = (const fvec4*)w;
  fvec4 w0 = wr[threadIdx.x], w1 = wr[threadIdx.x + 256];
  u16* orow = out + (size_t)t * D_;
  uint2 o0, o1;
  o0.x = (u32)f2bf(w0[0]*v0[0]*inv) | ((u32)f2bf(w0[1]*v0[1]*inv) << 16);
  o0.y = (u32)f2bf(w0[2]*v0[2]*inv) | ((u32)f2bf(w0[3]*v0[3]*inv) << 16);
  o1.x = (u32)f2bf(w1[0]*v1[0]*inv) | ((u32)f2bf(w1[1]*v1[1]*inv) << 16);
  o1.y = (u32)f2bf(w1[2]*v1[2]*inv) | ((u32)f2bf(w1[3]*v1[3]*inv) << 16);
  *(uint2*)(orow + threadIdx.x * 4) = o0;
  *(uint2*)(orow + (threadIdx.x + 256) * 4) = o1;
}

// -------- GEMM: C(MxN)=A(MxK)*B^T(NxK) bf16, split-K via blockIdx.z ----------
// EPI 0: Cf[z]=acc (partial)  EPI 3: silu-pair -> Cb bf16
template<int EPI>
__global__ __launch_bounds__(256)
void gemm_bt(const u16* __restrict__ A, const u16* __restrict__ B,
             float* __restrict__ Cf, u16* __restrict__ Cb,
             int K, int Ks, int ldC, long long zStride)
{
  __shared__ u16 lA[128 * 64];
  __shared__ u16 lB[128 * 64];
  const u16* Ab = A + (size_t)blockIdx.y * 128 * K;
  const u16* Bb = B + (size_t)blockIdx.x * 128 * K;
  int kz = blockIdx.z * Ks;

  int tid = threadIdx.x;
  int l = tid & 63;
  int wid = tid >> 6;
  int wr = wid >> 1, wc = wid & 1;
  int lrow = l & 15, lk = l >> 4;

  f32x4 acc[4][4] = {};

  for (int k0 = 0; k0 < Ks; k0 += 64) {
#pragma unroll
    for (int r = 0; r < 4; ++r) {
      int c = r * 256 + tid;
      int row = c >> 3, g = c & 7;
      int kel = kz + k0 + ((g ^ (row & 7)) << 3);
      gld16(Ab + (size_t)row * K + kel, (char*)lA + c * 16);
      gld16(Bb + (size_t)row * K + kel, (char*)lB + c * 16);
    }
    __syncthreads();
#pragma unroll
    for (int kk = 0; kk < 2; ++kk) {
      bf16x8 av[4], bv[4];
      int kbyte = (kk * 32 + lk * 8) * 2;
#pragma unroll
      for (int m = 0; m < 4; ++m) {
        int row = wr * 64 + m * 16 + lrow;
        int byt = (row * 128 + kbyte) ^ ((row & 7) << 4);
        av[m] = *(const bf16x8*)((const char*)lA + byt);
      }
#pragma unroll
      for (int n = 0; n < 4; ++n) {
        int row = wc * 64 + n * 16 + lrow;
        int byt = (row * 128 + kbyte) ^ ((row & 7) << 4);
        bv[n] = *(const bf16x8*)((const char*)lB + byt);
      }
#pragma unroll
      for (int m = 0; m < 4; ++m)
#pragma unroll
        for (int n = 0; n < 4; ++n)
          acc[m][n] = __builtin_amdgcn_mfma_f32_16x16x32_bf16(av[m], bv[n], acc[m][n], 0, 0, 0);
    }
    __syncthreads();
  }

  int grow0 = blockIdx.y * 128 + wr * 64 + lk * 4;
  if (EPI == 3) {
    int fcol0 = blockIdx.x * 64 + wc * 32 + lrow;
#pragma unroll
    for (int m = 0; m < 4; ++m)
#pragma unroll
      for (int np = 0; np < 2; ++np)
#pragma unroll
        for (int r = 0; r < 4; ++r) {
          float g = acc[m][2 * np][r], u = acc[m][2 * np + 1][r];
          float val = g / (1.f + __expf(-g)) * u;
          Cb[(size_t)(grow0 + m * 16 + r) * ldC + fcol0 + np * 16] = f2bf(val);
        }
    return;
  }
  float* Cz = Cf + (long long)blockIdx.z * zStride;
  int gcol0 = blockIdx.x * 128 + wc * 64 + lrow;
#pragma unroll
  for (int m = 0; m < 4; ++m)
#pragma unroll
    for (int n = 0; n < 4; ++n)
#pragma unroll
      for (int r = 0; r < 4; ++r) {
        size_t off = (size_t)(grow0 + m * 16 + r) * ldC + gcol0 + n * 16;
        Cz[off] = acc[m][n][r];
      }
}

// ------------- fused QKV post-process: tiled, fully coalesced ----------------
// grid (T/64, 32): z<16 Q head z | z<24 K kv=z-16 (+key_out transpose) | V kv=z-24
__global__ __launch_bounds__(256)
void qkvpost_k(const float* __restrict__ p0, const float* __restrict__ p1,
               const float* __restrict__ wq, const float* __restrict__ wk,
               const float* __restrict__ cosT, const float* __restrict__ sinT,
               const int* __restrict__ plp,
               u16* __restrict__ qr, u16* __restrict__ kr, u16* __restrict__ vT,
               float* __restrict__ key_out, float* __restrict__ val_out)
{
  __shared__ float tile[64][132];
  int t0 = blockIdx.x * 64;
  int z = blockIdx.y;
  int pl = plp[0];
  int tid = threadIdx.x;
  int cb = z < 16 ? z * 128 : (z < 24 ? 2048 + (z - 16) * 128 : 3072 + (z - 24) * 128);

  // load 64x128 tile = P0+P1 (rows stride 4096)
  {
    int r = tid >> 5;
    int c = (tid & 31) * 4;
#pragma unroll
    for (int i = 0; i < 8; ++i) {
      int row = i * 8 + r;
      size_t off = (size_t)(t0 + row) * 4096 + cb + c;
      fvec4 v = *(const fvec4*)(p0 + off) + *(const fvec4*)(p1 + off);
      *(fvec4*)&tile[row][c] = v;
    }
  }
  __syncthreads();

  if (z < 24) {
    // ---- RMS + RoPE: 4 threads per row, 32 d each ----
    int row = tid >> 2, q = tid & 3;
    int dbase = q * 32, pbase = (q ^ 2) * 32;
    const float* wn = z < 16 ? wq : wk;
    float sgn = (q < 2) ? -1.f : 1.f;
    fvec4 xv[8];
    float ss = 0.f;
#pragma unroll
    for (int j = 0; j < 8; ++j) {
      xv[j] = *(const fvec4*)&tile[row][dbase + j * 4];
      ss += xv[j][0]*xv[j][0] + xv[j][1]*xv[j][1] + xv[j][2]*xv[j][2] + xv[j][3]*xv[j][3];
    }
    ss += __shfl_xor(ss, 1);
    ss += __shfl_xor(ss, 2);
    float inv = rsqrtf(ss * (1.f / 128.f) + EPS_);
    int p = pl + t0 + row;
    float rv[32];
#pragma unroll
    for (int j = 0; j < 8; ++j) {
      fvec4 xo = *(const fvec4*)&tile[row][pbase + j * 4];
      fvec4 wv = *(const fvec4*)(wn + dbase + j * 4);
      fvec4 wo = *(const fvec4*)(wn + pbase + j * 4);
      fvec4 cs = *(const fvec4*)(cosT + (size_t)p * 128 + dbase + j * 4);
      fvec4 sn = *(const fvec4*)(sinT + (size_t)p * 128 + dbase + j * 4);
#pragma unroll
      for (int e = 0; e < 4; ++e) {
        float xn = wv[e] * xv[j][e] * inv;
        float xp = wo[e] * xo[e] * inv;
        rv[j * 4 + e] = xn * cs[e] + sgn * xp * sn[e];
      }
    }
    // write qr / kr (bf16, coalesced)
    union { u32 w[8]; uint4 q4[2]; } ob;
    u16* orow = (z < 16 ? qr + ((size_t)z * T_ + t0 + row) * 128
                        : kr + ((size_t)(z - 16) * T_ + t0 + row) * 128) + dbase;
#pragma unroll
    for (int j = 0; j < 8; ++j)
      ob.w[j] = (u32)f2bf(rv[2 * j]) | ((u32)f2bf(rv[2 * j + 1]) << 16);
    *(uint4*)orow = ob.q4[0];
#pragma unroll
    for (int j = 0; j < 8; ++j)
      ob.w[j] = (u32)f2bf(rv[16 + 2 * j]) | ((u32)f2bf(rv[17 + 2 * j]) << 16);
    *(uint4*)(orow + 16) = ob.q4[0];

    if (z >= 16) {
      // write rotated values back, then transpose to key_out [d][p]
      __syncthreads();
#pragma unroll
      for (int j = 0; j < 8; ++j) {
        fvec4 v; v[0] = rv[j*4]; v[1] = rv[j*4+1]; v[2] = rv[j*4+2]; v[3] = rv[j*4+3];
        *(fvec4*)&tile[row][dbase + j * 4] = v;
      }
      __syncthreads();
      int d = tid >> 1, cc = (tid & 1) * 32;
      float* kp = key_out + ((size_t)(z - 16) * 128 + d) * SMAX_ + pl + t0 + cc;
      if ((pl & 3) == 0) {
#pragma unroll
        for (int j4 = 0; j4 < 8; ++j4) {
          fvec4 v;
#pragma unroll
          for (int e = 0; e < 4; ++e) v[e] = tile[cc + j4 * 4 + e][d];
          *(fvec4*)(kp + j4 * 4) = v;
        }
      } else {
        for (int j = 0; j < 32; ++j) kp[j] = tile[cc + j][d];
      }
    }
  } else {
    // ---- V: val_out direct (row-major) + vT transpose (bf16) ----
    int kv = z - 24;
    int row = tid >> 2, q = tid & 3;
    float* vp = val_out + ((size_t)kv * SMAX_ + pl + t0 + row) * 128 + q * 32;
#pragma unroll
    for (int j = 0; j < 8; ++j)
      *(fvec4*)(vp + j * 4) = *(const fvec4*)&tile[row][q * 32 + j * 4];
    int d = tid >> 1, cc = (tid & 1) * 32;
    union { u32 w[8]; uint4 q4[2]; } ob;
    u16* tp = vT + ((size_t)kv * 128 + d) * T_ + t0 + cc;
#pragma unroll
    for (int j = 0; j < 8; ++j)
      ob.w[j] = (u32)f2bf(tile[cc + 2 * j][d]) | ((u32)f2bf(tile[cc + 2 * j + 1][d]) << 16);
    *(uint4*)tp = ob.q4[0];
    *(uint4*)(tp + 8) = ob.q4[1];
  }
}

// ---------------- flash attention: per (q-tile of 64, head) ------------------
__global__ __launch_bounds__(256)
void flash_k(const u16* __restrict__ qr, const u16* __restrict__ kr,
             const u16* __restrict__ vTb, const float* __restrict__ am,
             const int* __restrict__ plp, u16* __restrict__ ctx)
{
  __shared__ u16 lQ[QB * DH_];
  __shared__ u16 lKV[SB * DH_];
  __shared__ u16 lP[QB * SB];
  __shared__ float lScale[QB];
  __shared__ float lSum[QB];

  int qt = gridDim.x - 1 - blockIdx.x;   // heavy diagonal blocks first
  int h = blockIdx.y;
  int kvh = h >> 1;
  int pl = plp[0];
  int tid = threadIdx.x;
  int l = tid & 63, w = tid >> 6;
  int lrow = l & 15, lk = l >> 4;

  const u16* Qb = qr + ((size_t)h * T_ + qt * QB) * DH_;
  const u16* Kb = kr + (size_t)kvh * T_ * DH_;
  const u16* Vb = vTb + (size_t)kvh * DH_ * T_;

#pragma unroll
  for (int r = 0; r < 4; ++r) {
    int c = r * 256 + tid;
    int row = c >> 4, g = c & 15;
    gld16(Qb + (size_t)row * DH_ + ((g ^ (row & 7)) << 3), (char*)lQ + c * 16);
  }

  float m_run = -3.0e38f, l_run = 0.f;
  f32x4 acc_o[4][2] = {};

  int t_lo = qt * QB;
  int s_hi = min(T_, t_lo + QB + pl);
  int nt = (s_hi + SB - 1) / SB;
  int tcol = w * 16 + lrow;
  int tg = t_lo + tcol;

  for (int it = 0; it < nt; ++it) {
    int s0 = it * SB;
#pragma unroll
    for (int r = 0; r < 8; ++r) {
      int c = r * 256 + tid;
      int row = c >> 4, g = c & 15;
      gld16(Kb + (size_t)(s0 + row) * DH_ + ((g ^ (row & 7)) << 3), (char*)lKV + c * 16);
    }
    __syncthreads();

    f32x4 acc_s[8] = {};
#pragma unroll
    for (int kk = 0; kk < 4; ++kk) {
      int kbyte = kk * 64 + lk * 16;
      int trow = w * 16 + lrow;
      bf16x8 bq = *(const bf16x8*)((const char*)lQ + ((trow * 256 + kbyte) ^ ((trow & 7) << 4)));
#pragma unroll
      for (int m = 0; m < 8; ++m) {
        int srow = m * 16 + lrow;
        bf16x8 ak = *(const bf16x8*)((const char*)lKV + ((srow * 256 + kbyte) ^ ((srow & 7) << 4)));
        acc_s[m] = __builtin_amdgcn_mfma_f32_16x16x32_bf16(ak, bq, acc_s[m], 0, 0, 0);
      }
    }
    __syncthreads();

#pragma unroll
    for (int r = 0; r < 8; ++r) {
      int c = r * 256 + tid;
      int row = c >> 4, g = c & 15;
      gld16(Vb + (size_t)row * T_ + s0 + ((g ^ (row & 7)) << 3), (char*)lKV + c * 16);
    }

    bool full = (s0 + SB <= t_lo + pl + 1);
    float vmax = -3.0e38f;
    float sv[8][4];
    if (full) {
#pragma unroll
      for (int m = 0; m < 8; ++m)
#pragma unroll
        for (int r = 0; r < 4; ++r) {
          float val = acc_s[m][r]; sv[m][r] = val; vmax = fmaxf(vmax, val);
        }
    } else {
#pragma unroll
      for (int m = 0; m < 8; ++m) {
        int sg = s0 + m * 16 + lk * 4;
        fvec4 a4 = *(const fvec4*)(am + (size_t)tg * T_ + sg);
#pragma unroll
        for (int r = 0; r < 4; ++r) {
          float val = acc_s[m][r] + ((sg + r <= tg + pl) ? 0.f : -128.f * a4[r]);
          sv[m][r] = val; vmax = fmaxf(vmax, val);
        }
      }
    }
    vmax = fmaxf(vmax, __shfl_xor(vmax, 16));
    vmax = fmaxf(vmax, __shfl_xor(vmax, 32));
    float m_new = fmaxf(m_run, vmax);
    float corr = __expf(m_run - m_new);
    float psum = 0.f;
    u32 pw[8][2];
#pragma unroll
    for (int m = 0; m < 8; ++m) {
      float pq0 = __expf(sv[m][0] - m_new);
      float pq1 = __expf(sv[m][1] - m_new);
      float pq2 = __expf(sv[m][2] - m_new);
      float pq3 = __expf(sv[m][3] - m_new);
      psum += (pq0 + pq1) + (pq2 + pq3);
      pw[m][0] = (u32)f2bf(pq0) | ((u32)f2bf(pq1) << 16);
      pw[m][1] = (u32)f2bf(pq2) | ((u32)f2bf(pq3) << 16);
    }
    psum += __shfl_xor(psum, 16);
    psum += __shfl_xor(psum, 32);
    l_run = l_run * corr + psum;
    m_run = m_new;
    if (lk == 0) lScale[tcol] = corr;
#pragma unroll
    for (int m = 0; m < 8; ++m) {
      int byt = (tcol * 256 + m * 32 + lk * 8) ^ ((tcol & 7) << 4);
      *(uint2*)((char*)lP + byt) = make_uint2(pw[m][0], pw[m][1]);
    }
    __syncthreads();

#pragma unroll
    for (int m = 0; m < 4; ++m) {
      fvec4 c4 = *(const fvec4*)&lScale[m * 16 + lk * 4];
#pragma unroll
      for (int n = 0; n < 2; ++n)
#pragma unroll
        for (int r = 0; r < 4; ++r) acc_o[m][n][r] *= c4[r];
    }
#pragma unroll
    for (int kk = 0; kk < 4; ++kk) {
      int kbyte = kk * 64 + lk * 16;
      bf16x8 ap[4], bv[2];
#pragma unroll
      for (int m = 0; m < 4; ++m) {
        int trow = m * 16 + lrow;
        ap[m] = *(const bf16x8*)((const char*)lP + ((trow * 256 + kbyte) ^ ((trow & 7) << 4)));
      }
#pragma unroll
      for (int n = 0; n < 2; ++n) {
        int drow = w * 32 + n * 16 + lrow;
        bv[n] = *(const bf16x8*)((const char*)lKV + ((drow * 256 + kbyte) ^ ((drow & 7) << 4)));
      }
#pragma unroll
      for (int m = 0; m < 4; ++m)
#pragma unroll
        for (int n = 0; n < 2; ++n)
          acc_o[m][n] = __builtin_amdgcn_mfma_f32_16x16x32_bf16(ap[m], bv[n], acc_o[m][n], 0, 0, 0);
    }
    __syncthreads();
  }

  if (lk == 0) lSum[tcol] = l_run;
  __syncthreads();
#pragma unroll
  for (int m = 0; m < 4; ++m) {
    fvec4 s4 = *(const fvec4*)&lSum[m * 16 + lk * 4];
#pragma unroll
    for (int r = 0; r < 4; ++r) {
      float inv = 1.f / s4[r];
      int trow = t_lo + m * 16 + lk * 4 + r;
      u16* crow = ctx + (size_t)trow * (H_ * DH_) + h * DH_;
#pragma unroll
      for (int n = 0; n < 2; ++n) {
        int d = w * 32 + n * 16 + lrow;
        crow[d] = f2bf(acc_o[m][n][r] * inv);
      }
    }
  }
}

// ---------------- final RMS (last token) + partial combine -------------------
__global__ void frms_k(const float* __restrict__ x, const float* __restrict__ p0,
                       const float* __restrict__ p1, const float* __restrict__ w,
                       float* __restrict__ out)
{
  __shared__ float sm[4];
  float s = 0.f;
  for (int d = threadIdx.x; d < D_; d += 256) {
    float v = x[d] + p0[d] + p1[d];
    s += v * v;
  }
  s = blk_sum(s, sm);
  float inv = rsqrtf(s * (1.f / D_) + EPS_);
  for (int d = threadIdx.x; d < D_; d += 256)
    out[d] = w[d] * (x[d] + p0[d] + p1[d]) * inv;
}

// ---------------- LM head partial GEMV (f32) ---------------------------------
__global__ void lmgemv_k(const float* __restrict__ last, const float* __restrict__ Wlm,
                         float* __restrict__ part)
{
  __shared__ float ls[256];
  int v = blockIdx.x * 256 + threadIdx.x;
  int c = blockIdx.y;
  ls[threadIdx.x] = last[c * 256 + threadIdx.x];
  __syncthreads();
  const float* Wp = Wlm + (size_t)c * 256 * V_ + v;
  float acc = 0.f;
#pragma unroll 8
  for (int d = 0; d < 256; d++) acc += ls[d] * Wp[(size_t)d * V_];
  part[(size_t)c * V_ + v] = acc;
}

__global__ void amax_part_k(const float* __restrict__ part, float2* __restrict__ out)
{
  __shared__ float sv[4];
  __shared__ int si[4];
  int v = blockIdx.x * 256 + threadIdx.x;
  float val = 0.f;
#pragma unroll
  for (int c = 0; c < 8; c++) val += part[(size_t)c * V_ + v];
  float bv = val; int bi = v;
#pragma unroll
  for (int m = 32; m; m >>= 1) {
    float ov = __shfl_xor(bv, m);
    int oi = __shfl_xor(bi, m);
    if (ov > bv || (ov == bv && oi < bi)) { bv = ov; bi = oi; }
  }
  if ((threadIdx.x & 63) == 0) { sv[threadIdx.x >> 6] = bv; si[threadIdx.x >> 6] = bi; }
  __syncthreads();
  if (threadIdx.x == 0) {
    for (int w = 1; w < 4; w++)
      if (sv[w] > bv || (sv[w] == bv && si[w] < bi)) { bv = sv[w]; bi = si[w]; }
    out[blockIdx.x] = make_float2(bv, (float)bi);
  }
}

__global__ void finalize_k(const float2* __restrict__ part, int np,
                           const int* __restrict__ plp, float* __restrict__ dout,
                           unsigned long long lastoff)
{
  if (threadIdx.x == 0) {
    float bv = part[0].x; int bi = (int)part[0].y;
    for (int b = 1; b < np; b++) {
      float v = part[b].x; int i = (int)part[b].y;
      if (v > bv || (v == bv && i < bi)) { bv = v; bi = i; }
    }
    dout[0] = (float)bi;
    dout[lastoff] = (float)(plp[0] + T_);
  }
}

// =============================================================================
extern "C" void kernel_launch(void* const* d_in, const int* in_sizes, int n_in,
                              void* d_out, int out_size, void* d_ws, size_t ws_size,
                              hipStream_t stream)
{
  (void)in_sizes; (void)n_in; (void)out_size; (void)ws_size;

  const float* key_in  = (const float*)d_in[0];
  const float* val_in  = (const float*)d_in[1];
  const int*   ids     = (const int*)d_in[2];
  const float* am      = (const float*)d_in[3];
  const int*   plp     = (const int*)d_in[4];
  const void*  edata   = d_in[5];
  const float* esc     = (const float*)d_in[6];
  const float* ez      = (const float*)d_in[7];
  const float* cosT    = (const float*)d_in[8];
  const float* sinT    = (const float*)d_in[9];
  const float* w_in_ln = (const float*)d_in[10];
  const float* Wq      = (const float*)d_in[11];
  const float* Wk      = (const float*)d_in[12];
  const float* Wv      = (const float*)d_in[13];
  const float* wqn     = (const float*)d_in[14];
  const float* wkn     = (const float*)d_in[15];
  const float* Wo      = (const float*)d_in[16];
  const float* wpost   = (const float*)d_in[17];
  const float* Wg      = (const float*)d_in[18];
  const float* Wu      = (const float*)d_in[19];
  const float* Wd      = (const float*)d_in[20];
  const float* wfin    = (const float*)d_in[21];
  const float* Wlm     = (const float*)d_in[22];

  float* out = (float*)d_out;
  const size_t KVN = (size_t)L_ * KVH_ * DH_ * SMAX_; // 8388608
  float* key_out = out + 1;
  float* val_out = out + 1 + KVN;
  unsigned long long lastoff = 1 + 2 * KVN;

  char* ws = (char*)d_ws;
  u16*   wT     = (u16*)  (ws + 0);            // 50,331,648
  u16*   hn     = (u16*)  (ws + 50331648);     //  4,194,304
  float* P0     = (float*)(ws + 54525952);     // 16,777,216
  float* P1     = (float*)(ws + 71303168);     // 16,777,216
  u16*   qr     = (u16*)  (ws + 88080384);     //  4,194,304
  u16*   kr     = (u16*)  (ws + 92274688);     //  2,097,152
  u16*   vT     = (u16*)  (ws + 94371840);     //  2,097,152
  u16*   ctx    = (u16*)  (ws + 96468992);     //  4,194,304
  float* hidden = (float*)(ws + 100663296);    //  8,388,608
  u16*   mlp    = (u16*)  (ws + 109051904);    // 12,582,912
  float* last   = (float*)(ws + 121634816);    //      8,192
  float* lpart  = (float*)(ws + 121643008);    //  1,024,000
  float2* amaxp = (float2*)(ws + 122667008);   //      4,096

  const long long ZS = 4194304;

  hipMemcpyAsync(key_out, key_in, KVN * sizeof(float), hipMemcpyDeviceToDevice, stream);
  hipMemcpyAsync(val_out, val_in, KVN * sizeof(float), hipMemcpyDeviceToDevice, stream);
  embed_k<<<T_, 256, 0, stream>>>(ids, edata, esc, ez, hidden);

  for (int i = 0; i < L_; i++) {
    // --- attention ---
    if (i == 0)
      rms_k<0><<<T_, 256, 0, stream>>>(hidden, nullptr, nullptr, w_in_ln, hn);
    else
      rms_k<1><<<T_, 256, 0, stream>>>(hidden, P0, P1, w_in_ln + (size_t)i * D_, hn);

    convT2_k<<<dim3(64, 32), 256, 0, stream>>>(
        Wq + (size_t)i * 4194304, Wk + (size_t)i * 2097152, Wv + (size_t)i * 2097152,
        32, 48, 2048, 1024, 1024, 0, 2048, 3072, 2048, wT, 0);
    gemm_bt<0><<<dim3(32, 8, 2), 256, 0, stream>>>(hn, wT, P0, nullptr, 2048, 1024, 4096, ZS);

    qkvpost_k<<<dim3(T_ / 64, 32), 256, 0, stream>>>(P0, P1,
        wqn + (size_t)i * DH_, wkn + (size_t)i * DH_, cosT, sinT, plp,
        qr, kr, vT,
        key_out + (size_t)i * KVH_ * DH_ * SMAX_,
        val_out + (size_t)i * KVH_ * SMAX_ * DH_);

    flash_k<<<dim3(T_ / QB, H_), 256, 0, stream>>>(qr, kr, vT, am, plp, ctx);

    convT2_k<<<dim3(32, 32), 256, 0, stream>>>(
        Wo + (size_t)i * 4194304, nullptr, nullptr,
        32, 64, 2048, 2048, 2048, 0, 0, 0, 2048, wT, 0);
    gemm_bt<0><<<dim3(16, 8, 2), 256, 0, stream>>>(ctx, wT, P0, nullptr, 2048, 1024, 2048, ZS);

    // --- MLP ---
    rms_k<1><<<T_, 256, 0, stream>>>(hidden, P0, P1, wpost + (size_t)i * D_, hn);

    convT2_k<<<dim3(192, 32), 256, 0, stream>>>(
        Wg + (size_t)i * 12582912, Wu + (size_t)i * 12582912, Wu + (size_t)i * 12582912,
        96, 192, 6144, 6144, 6144, 0, 16, 16, 2048, wT, 1);
    gemm_bt<3><<<dim3(96, 8, 1), 256, 0, stream>>>(hn, wT, nullptr, mlp, 2048, 2048, 6144, 0);

    convT2_k<<<dim3(32, 96), 256, 0, stream>>>(
        Wd + (size_t)i * 12582912, nullptr, nullptr,
        32, 64, 2048, 2048, 2048, 0, 0, 0, 6144, wT, 0);
    gemm_bt<0><<<dim3(16, 8, 2), 256, 0, stream>>>(mlp, wT, P0, nullptr, 6144, 3072, 2048, ZS);
  }

  frms_k<<<1, 256, 0, stream>>>(hidden + (size_t)(T_ - 1) * D_,
                                P0 + (size_t)(T_ - 1) * D_, P1 + (size_t)(T_ - 1) * D_,
                                wfin, last);
  lmgemv_k<<<dim3(V_ / 256, 8), 256, 0, stream>>>(last, Wlm, lpart);
  amax_part_k<<<V_ / 256, 256, 0, stream>>>(lpart, amaxp);
  finalize_k<<<1, 64, 0, stream>>>(amaxp, V_ / 256, plp, out, lastoff);
}

// Round 5
// 1198.525 us; speedup vs baseline: 2.0201x; 1.0774x over previous
//
#include <hip/hip_runtime.h>
#include <cstdint>

#define L_ 4
#define D_ 2048
#define H_ 16
#define KVH_ 8
#define DH_ 128
#define F_ 6144
#define V_ 32000
#define SMAX_ 2048
#define T_ 1024
#define EPS_ 1e-6f
#define QB 32
#define SB 128
#define ZSE 4194304  // elements between split-K partial planes (16 MB)

typedef unsigned short u16;
typedef unsigned int u32;
typedef float fvec4 __attribute__((ext_vector_type(4)));
typedef float f32x4 __attribute__((ext_vector_type(4)));
typedef __bf16 bf16x8 __attribute__((ext_vector_type(8)));

__device__ __forceinline__ u16 f2bf(float f) {
  union { float f; u32 u; } a; a.f = f;
  u32 u = a.u;
  return (u16)((u + 0x7FFFu + ((u >> 16) & 1u)) >> 16);
}

__device__ __forceinline__ void gld16(const void* g, void* l) {
  __builtin_amdgcn_global_load_lds(
      (const __attribute__((address_space(1))) void*)g,
      (__attribute__((address_space(3))) void*)l, 16, 0, 0);
}

__device__ __forceinline__ float blk_sum(float v, volatile float* sm) {
#pragma unroll
  for (int m = 32; m; m >>= 1) v += __shfl_xor(v, m);
  if ((threadIdx.x & 63) == 0) sm[threadIdx.x >> 6] = v;
  __syncthreads();
  v = sm[0] + sm[1] + sm[2] + sm[3];
  __syncthreads();
  return v;
}

// ---------------- embedding (uint8-vs-int32 runtime detection) ---------------
__global__ void embed_k(const int* __restrict__ ids, const void* __restrict__ edata,
                        const float* __restrict__ esc, const float* __restrict__ ez,
                        float* __restrict__ hidden)
{
  const int* ei = (const int*)edata;
  int chk = ei[threadIdx.x & 63];
  bool ok = ((unsigned)chk) <= 255u;
  bool is_i32 = (__ballot(ok) == ~0ULL);
  int t = blockIdx.x;
  int id = ids[t];
  float sc = esc[id], zp = ez[id];
  size_t base = (size_t)id * D_;
  const uint8_t* eb = (const uint8_t*)edata;
  for (int d = threadIdx.x; d < D_; d += 256) {
    float e = is_i32 ? (float)ei[base + d] : (float)eb[base + d];
    hidden[(size_t)t * D_ + d] = e * sc + zp;
  }
}

// ------ convT v2: up to 3 segments, fvec4 loads, [64][65] f32 LDS ------------
__global__ __launch_bounds__(256)
void convT2_k(const float* __restrict__ W0, const float* __restrict__ W1,
              const float* __restrict__ W2,
              int x1, int x2, int N0, int N1, int N2,
              int r0, int r1, int r2, int K, u16* __restrict__ WT, int gu)
{
  __shared__ float tile[64][65];
  int x = blockIdx.x, k0 = blockIdx.y * 64;
  const float* W; int N, nb, rb;
  if (x < x1)      { W = W0; N = N0; nb = x;      rb = r0; }
  else if (x < x2) { W = W1; N = N1; nb = x - x1; rb = r1; }
  else             { W = W2; N = N2; nb = x - x2; rb = r2; }
  int n0 = nb * 64;
  int tid = threadIdx.x;
  int lk = tid >> 4, n4 = (tid & 15) * 4;
#pragma unroll
  for (int i = 0; i < 4; ++i) {
    int kr = i * 16 + lk;
    fvec4 v = *(const fvec4*)(W + (size_t)(k0 + kr) * N + n0 + n4);
#pragma unroll
    for (int j = 0; j < 4; ++j) tile[n4 + j][kr] = v[j];
  }
  __syncthreads();
  int n = tid >> 2, kq = (tid & 3) * 16;
  int f = n0 + n;
  int row = gu ? (rb + ((f >> 4) << 5) + (f & 15)) : (rb + f);
  union { u16 h[16]; uint4 q[2]; } o;
#pragma unroll
  for (int i = 0; i < 16; ++i) o.h[i] = f2bf(tile[n][kq + i]);
  u16* op = WT + (size_t)row * K + k0 + kq;
  *(uint4*)op = o.q[0];
  *(uint4*)(op + 8) = o.q[1];
}

// ---------------- RMS norm f32 -> bf16; NZ: x += sum of NZ partials ----------
template<int NZ>
__global__ void rms_k(float* __restrict__ x, const float* __restrict__ p,
                      const float* __restrict__ w, u16* __restrict__ out)
{
  __shared__ float sm[4];
  int t = blockIdx.x;
  fvec4* xr = (fvec4*)(x + (size_t)t * D_);
  fvec4 v0 = xr[threadIdx.x], v1 = xr[threadIdx.x + 256];
  if (NZ > 0) {
#pragma unroll
    for (int z = 0; z < NZ; ++z) {
      const fvec4* a = (const fvec4*)(p + (size_t)z * ZSE + (size_t)t * D_);
      v0 += a[threadIdx.x];
      v1 += a[threadIdx.x + 256];
    }
    xr[threadIdx.x] = v0;
    xr[threadIdx.x + 256] = v1;
  }
  float s = v0[0]*v0[0] + v0[1]*v0[1] + v0[2]*v0[2] + v0[3]*v0[3]
          + v1[0]*v1[0] + v1[1]*v1[1] + v1[2]*v1[2] + v1[3]*v1[3];
  s = blk_sum(s, sm);
  float inv = rsqrtf(s * (1.f / D_) + EPS_);
  const fvec4* wr = (const fvec4*)w;
  fvec4 w0 = wr[threadIdx.x], w1 = wr[threadIdx.x + 256];
  u16* orow = out + (size_t)t * D_;
  uint2 o0, o1;
  o0.x = (u32)f2bf(w0[0]*v0[0]*inv) | ((u32)f2bf(w0[1]*v0[1]*inv) << 16);
  o0.y = (u32)f2bf(w0[2]*v0[2]*inv) | ((u32)f2bf(w0[3]*v0[3]*inv) << 16);
  o1.x = (u32)f2bf(w1[0]*v1[0]*inv) | ((u32)f2bf(w1[1]*v1[1]*inv) << 16);
  o1.y = (u32)f2bf(w1[2]*v1[2]*inv) | ((u32)f2bf(w1[3]*v1[3]*inv) << 16);
  *(uint2*)(orow + threadIdx.x * 4) = o0;
  *(uint2*)(orow + (threadIdx.x + 256) * 4) = o1;
}

// -------- GEMM: C(MxN)=A(MxK)*B^T(NxK) bf16, split-K via blockIdx.z ----------
// EPI 0: Cf[z]=acc (partial)  EPI 3: silu-pair -> Cb bf16
template<int EPI>
__global__ __launch_bounds__(256)
void gemm_bt(const u16* __restrict__ A, const u16* __restrict__ B,
             float* __restrict__ Cf, u16* __restrict__ Cb,
             int K, int Ks, int ldC, long long zStride)
{
  __shared__ u16 lA[128 * 64];
  __shared__ u16 lB[128 * 64];
  const u16* Ab = A + (size_t)blockIdx.y * 128 * K;
  const u16* Bb = B + (size_t)blockIdx.x * 128 * K;
  int kz = blockIdx.z * Ks;

  int tid = threadIdx.x;
  int l = tid & 63;
  int wid = tid >> 6;
  int wr = wid >> 1, wc = wid & 1;
  int lrow = l & 15, lk = l >> 4;

  f32x4 acc[4][4] = {};

  for (int k0 = 0; k0 < Ks; k0 += 64) {
#pragma unroll
    for (int r = 0; r < 4; ++r) {
      int c = r * 256 + tid;
      int row = c >> 3, g = c & 7;
      int kel = kz + k0 + ((g ^ (row & 7)) << 3);
      gld16(Ab + (size_t)row * K + kel, (char*)lA + c * 16);
      gld16(Bb + (size_t)row * K + kel, (char*)lB + c * 16);
    }
    __syncthreads();
#pragma unroll
    for (int kk = 0; kk < 2; ++kk) {
      bf16x8 av[4], bv[4];
      int kbyte = (kk * 32 + lk * 8) * 2;
#pragma unroll
      for (int m = 0; m < 4; ++m) {
        int row = wr * 64 + m * 16 + lrow;
        int byt = (row * 128 + kbyte) ^ ((row & 7) << 4);
        av[m] = *(const bf16x8*)((const char*)lA + byt);
      }
#pragma unroll
      for (int n = 0; n < 4; ++n) {
        int row = wc * 64 + n * 16 + lrow;
        int byt = (row * 128 + kbyte) ^ ((row & 7) << 4);
        bv[n] = *(const bf16x8*)((const char*)lB + byt);
      }
#pragma unroll
      for (int m = 0; m < 4; ++m)
#pragma unroll
        for (int n = 0; n < 4; ++n)
          acc[m][n] = __builtin_amdgcn_mfma_f32_16x16x32_bf16(av[m], bv[n], acc[m][n], 0, 0, 0);
    }
    __syncthreads();
  }

  int grow0 = blockIdx.y * 128 + wr * 64 + lk * 4;
  if (EPI == 3) {
    int fcol0 = blockIdx.x * 64 + wc * 32 + lrow;
#pragma unroll
    for (int m = 0; m < 4; ++m)
#pragma unroll
      for (int np = 0; np < 2; ++np)
#pragma unroll
        for (int r = 0; r < 4; ++r) {
          float g = acc[m][2 * np][r], u = acc[m][2 * np + 1][r];
          float val = g / (1.f + __expf(-g)) * u;
          Cb[(size_t)(grow0 + m * 16 + r) * ldC + fcol0 + np * 16] = f2bf(val);
        }
    return;
  }
  float* Cz = Cf + (long long)blockIdx.z * zStride;
  int gcol0 = blockIdx.x * 128 + wc * 64 + lrow;
#pragma unroll
  for (int m = 0; m < 4; ++m)
#pragma unroll
    for (int n = 0; n < 4; ++n)
#pragma unroll
      for (int r = 0; r < 4; ++r) {
        size_t off = (size_t)(grow0 + m * 16 + r) * ldC + gcol0 + n * 16;
        Cz[off] = acc[m][n][r];
      }
}

// ------------- fused QKV post-process: tiled, fully coalesced ----------------
// grid (T/64, 32): z<16 Q head z | z<24 K kv=z-16 (+key_out transpose) | V kv=z-24
__global__ __launch_bounds__(256)
void qkvpost_k(const float* __restrict__ p0, const float* __restrict__ p1,
               const float* __restrict__ wq, const float* __restrict__ wk,
               const float* __restrict__ cosT, const float* __restrict__ sinT,
               const int* __restrict__ plp,
               u16* __restrict__ qr, u16* __restrict__ kr, u16* __restrict__ vT,
               float* __restrict__ key_out, float* __restrict__ val_out)
{
  __shared__ float tile[64][132];
  int t0 = blockIdx.x * 64;
  int z = blockIdx.y;
  int pl = plp[0];
  int tid = threadIdx.x;
  int cb = z < 16 ? z * 128 : (z < 24 ? 2048 + (z - 16) * 128 : 3072 + (z - 24) * 128);

  // load 64x128 tile = P0+P1 (rows stride 4096)
  {
    int r = tid >> 5;
    int c = (tid & 31) * 4;
#pragma unroll
    for (int i = 0; i < 8; ++i) {
      int row = i * 8 + r;
      size_t off = (size_t)(t0 + row) * 4096 + cb + c;
      fvec4 v = *(const fvec4*)(p0 + off) + *(const fvec4*)(p1 + off);
      *(fvec4*)&tile[row][c] = v;
    }
  }
  __syncthreads();

  if (z < 24) {
    // ---- RMS + RoPE: 4 threads per row, 32 d each ----
    int row = tid >> 2, q = tid & 3;
    int dbase = q * 32, pbase = (q ^ 2) * 32;
    const float* wn = z < 16 ? wq : wk;
    float sgn = (q < 2) ? -1.f : 1.f;
    fvec4 xv[8];
    float ss = 0.f;
#pragma unroll
    for (int j = 0; j < 8; ++j) {
      xv[j] = *(const fvec4*)&tile[row][dbase + j * 4];
      ss += xv[j][0]*xv[j][0] + xv[j][1]*xv[j][1] + xv[j][2]*xv[j][2] + xv[j][3]*xv[j][3];
    }
    ss += __shfl_xor(ss, 1);
    ss += __shfl_xor(ss, 2);
    float inv = rsqrtf(ss * (1.f / 128.f) + EPS_);
    int p = pl + t0 + row;
    float rv[32];
#pragma unroll
    for (int j = 0; j < 8; ++j) {
      fvec4 xo = *(const fvec4*)&tile[row][pbase + j * 4];
      fvec4 wv = *(const fvec4*)(wn + dbase + j * 4);
      fvec4 wo = *(const fvec4*)(wn + pbase + j * 4);
      fvec4 cs = *(const fvec4*)(cosT + (size_t)p * 128 + dbase + j * 4);
      fvec4 sn = *(const fvec4*)(sinT + (size_t)p * 128 + dbase + j * 4);
#pragma unroll
      for (int e = 0; e < 4; ++e) {
        float xn = wv[e] * xv[j][e] * inv;
        float xp = wo[e] * xo[e] * inv;
        rv[j * 4 + e] = xn * cs[e] + sgn * xp * sn[e];
      }
    }
    // write qr / kr (bf16, coalesced) — full 32 elements (R4 bug: q4[1] dropped)
    union { u32 w[8]; uint4 q4[2]; } ob;
    u16* orow = (z < 16 ? qr + ((size_t)z * T_ + t0 + row) * 128
                        : kr + ((size_t)(z - 16) * T_ + t0 + row) * 128) + dbase;
#pragma unroll
    for (int j = 0; j < 8; ++j)
      ob.w[j] = (u32)f2bf(rv[2 * j]) | ((u32)f2bf(rv[2 * j + 1]) << 16);
    *(uint4*)orow = ob.q4[0];
    *(uint4*)(orow + 8) = ob.q4[1];
#pragma unroll
    for (int j = 0; j < 8; ++j)
      ob.w[j] = (u32)f2bf(rv[16 + 2 * j]) | ((u32)f2bf(rv[17 + 2 * j]) << 16);
    *(uint4*)(orow + 16) = ob.q4[0];
    *(uint4*)(orow + 24) = ob.q4[1];

    if (z >= 16) {
      // write rotated values back, then transpose to key_out [d][p]
      __syncthreads();
#pragma unroll
      for (int j = 0; j < 8; ++j) {
        fvec4 v; v[0] = rv[j*4]; v[1] = rv[j*4+1]; v[2] = rv[j*4+2]; v[3] = rv[j*4+3];
        *(fvec4*)&tile[row][dbase + j * 4] = v;
      }
      __syncthreads();
      int d = tid >> 1, cc = (tid & 1) * 32;
      float* kp = key_out + ((size_t)(z - 16) * 128 + d) * SMAX_ + pl + t0 + cc;
      if ((pl & 3) == 0) {
#pragma unroll
        for (int j4 = 0; j4 < 8; ++j4) {
          fvec4 v;
#pragma unroll
          for (int e = 0; e < 4; ++e) v[e] = tile[cc + j4 * 4 + e][d];
          *(fvec4*)(kp + j4 * 4) = v;
        }
      } else {
        for (int j = 0; j < 32; ++j) kp[j] = tile[cc + j][d];
      }
    }
  } else {
    // ---- V: val_out direct (row-major) + vT transpose (bf16) ----
    int kv = z - 24;
    int row = tid >> 2, q = tid & 3;
    float* vp = val_out + ((size_t)kv * SMAX_ + pl + t0 + row) * 128 + q * 32;
#pragma unroll
    for (int j = 0; j < 8; ++j)
      *(fvec4*)(vp + j * 4) = *(const fvec4*)&tile[row][q * 32 + j * 4];
    int d = tid >> 1, cc = (tid & 1) * 32;
    union { u32 w[8]; uint4 q4[2]; } ob;
    u16* tp = vT + ((size_t)kv * 128 + d) * T_ + t0 + cc;
#pragma unroll
    for (int j = 0; j < 8; ++j)
      ob.w[j] = (u32)f2bf(tile[cc + 2 * j][d]) | ((u32)f2bf(tile[cc + 2 * j + 1][d]) << 16);
    *(uint4*)tp = ob.q4[0];
    *(uint4*)(tp + 8) = ob.q4[1];
  }
}

// ---------------- flash attention: QB=32, waves split s-range 2x2 ------------
__global__ __launch_bounds__(256)
void flash_k(const u16* __restrict__ qr, const u16* __restrict__ kr,
             const u16* __restrict__ vTb, const float* __restrict__ am,
             const int* __restrict__ plp, u16* __restrict__ ctx)
{
  __shared__ u16 lQ[QB * DH_];    // 8 KB
  __shared__ u16 lKV[SB * DH_];   // 32 KB (K tile, then V tile)
  __shared__ u16 lP[QB * SB];     // 8 KB
  __shared__ float lMax[2][2][16];
  __shared__ float lSum[2][2][16];
  __shared__ float lScale[QB];
  __shared__ float lFin[QB];

  int qt = gridDim.x - 1 - blockIdx.x;   // heavy diagonal blocks first
  int h = blockIdx.y;
  int kvh = h >> 1;
  int pl = plp[0];
  int tid = threadIdx.x;
  int l = tid & 63, w = tid >> 6;
  int lrow = l & 15, lk = l >> 4;
  int tb = w & 1, sh = w >> 1;           // t-block (16 cols), s-half (64 rows)
  int tcol = tb * 16 + lrow;

  const u16* Qb = qr + ((size_t)h * T_ + qt * QB) * DH_;
  const u16* Kb = kr + (size_t)kvh * T_ * DH_;
  const u16* Vb = vTb + (size_t)kvh * DH_ * T_;

  // stage Q (32 x 128): 512 16B units
#pragma unroll
  for (int r = 0; r < 2; ++r) {
    int c = r * 256 + tid;
    int row = c >> 4, g = c & 15;
    gld16(Qb + (size_t)row * DH_ + ((g ^ (row & 7)) << 3), (char*)lQ + c * 16);
  }

  float m_run = -3.0e38f, l_run = 0.f;
  f32x4 acc_o[2][2] = {};   // t-frag m (2), d-frag n (2, wave d-slice w*32)

  int t_lo = qt * QB;
  int s_hi = min(T_, t_lo + QB + pl);
  int nt = (s_hi + SB - 1) / SB;
  int tg = t_lo + tcol;

  for (int it = 0; it < nt; ++it) {
    int s0 = it * SB;
#pragma unroll
    for (int r = 0; r < 8; ++r) {
      int c = r * 256 + tid;
      int row = c >> 4, g = c & 15;
      gld16(Kb + (size_t)(s0 + row) * DH_ + ((g ^ (row & 7)) << 3), (char*)lKV + c * 16);
    }
    __syncthreads();   // B1: K (and Q) staged

    // S^T: wave computes s-rows [sh*64, +64), t-cols [tb*16, +16)
    f32x4 acc_s[4] = {};
#pragma unroll
    for (int kk = 0; kk < 4; ++kk) {
      int kbyte = kk * 64 + lk * 16;
      int trow = tb * 16 + lrow;
      bf16x8 bq = *(const bf16x8*)((const char*)lQ + ((trow * 256 + kbyte) ^ ((trow & 7) << 4)));
#pragma unroll
      for (int m = 0; m < 4; ++m) {
        int srow = sh * 64 + m * 16 + lrow;
        bf16x8 ak = *(const bf16x8*)((const char*)lKV + ((srow * 256 + kbyte) ^ ((srow & 7) << 4)));
        acc_s[m] = __builtin_amdgcn_mfma_f32_16x16x32_bf16(ak, bq, acc_s[m], 0, 0, 0);
      }
    }
    __syncthreads();   // B2: all waves done reading K

    // stage V tile (128 d-rows x 128 s-cols) into lKV
#pragma unroll
    for (int r = 0; r < 8; ++r) {
      int c = r * 256 + tid;
      int row = c >> 4, g = c & 15;
      gld16(Vb + (size_t)row * T_ + s0 + ((g ^ (row & 7)) << 3), (char*)lKV + c * 16);
    }

    // mask + local max over this wave's 16 s-values per t-col
    bool full = (s0 + SB <= t_lo + pl + 1);
    float sv[4][4];
    float vmax = -3.0e38f;
    if (full) {
#pragma unroll
      for (int m = 0; m < 4; ++m)
#pragma unroll
        for (int r = 0; r < 4; ++r) {
          float val = acc_s[m][r]; sv[m][r] = val; vmax = fmaxf(vmax, val);
        }
    } else {
#pragma unroll
      for (int m = 0; m < 4; ++m) {
        int sg = s0 + sh * 64 + m * 16 + lk * 4;
        fvec4 a4 = *(const fvec4*)(am + (size_t)tg * T_ + sg);
#pragma unroll
        for (int r = 0; r < 4; ++r) {
          float val = acc_s[m][r] + ((sg + r <= tg + pl) ? 0.f : -128.f * a4[r]);
          sv[m][r] = val; vmax = fmaxf(vmax, val);
        }
      }
    }
    vmax = fmaxf(vmax, __shfl_xor(vmax, 16));
    vmax = fmaxf(vmax, __shfl_xor(vmax, 32));
    if (lk == 0) lMax[tb][sh][lrow] = vmax;
    __syncthreads();   // B3: cross-wave max visible

    float om = fmaxf(lMax[tb][0][lrow], lMax[tb][1][lrow]);
    float m_new = fmaxf(m_run, om);
    float corr = __expf(m_run - m_new);
    float psum = 0.f;
    u32 pw[4][2];
#pragma unroll
    for (int m = 0; m < 4; ++m) {
      float p0 = __expf(sv[m][0] - m_new);
      float p1 = __expf(sv[m][1] - m_new);
      float p2 = __expf(sv[m][2] - m_new);
      float p3 = __expf(sv[m][3] - m_new);
      psum += (p0 + p1) + (p2 + p3);
      pw[m][0] = (u32)f2bf(p0) | ((u32)f2bf(p1) << 16);
      pw[m][1] = (u32)f2bf(p2) | ((u32)f2bf(p3) << 16);
    }
    psum += __shfl_xor(psum, 16);
    psum += __shfl_xor(psum, 32);
    if (lk == 0) lSum[tb][sh][lrow] = psum;
    if (lk == 0 && sh == 0) lScale[tcol] = corr;
    // write P[t][s-local]: this wave's s-half
#pragma unroll
    for (int m = 0; m < 4; ++m) {
      int byt = (tcol * 256 + sh * 128 + m * 32 + lk * 8) ^ ((tcol & 7) << 4);
      *(uint2*)((char*)lP + byt) = make_uint2(pw[m][0], pw[m][1]);
    }
    __syncthreads();   // B4: P/sums/scale visible + V landed

    l_run = l_run * corr + lSum[tb][0][lrow] + lSum[tb][1][lrow];
    m_run = m_new;
    // rescale acc_o rows t = m*16 + lk*4 + r
#pragma unroll
    for (int m = 0; m < 2; ++m) {
      fvec4 c4 = *(const fvec4*)&lScale[m * 16 + lk * 4];
#pragma unroll
      for (int n = 0; n < 2; ++n)
#pragma unroll
        for (int r = 0; r < 4; ++r) acc_o[m][n][r] *= c4[r];
    }
    // PV: C[t][d] += P(t,s) . V^T(d,s); wave d-slice w*32
#pragma unroll
    for (int kk = 0; kk < 4; ++kk) {
      int kbyte = kk * 64 + lk * 16;
      bf16x8 ap[2], bv[2];
#pragma unroll
      for (int m = 0; m < 2; ++m) {
        int trow = m * 16 + lrow;
        ap[m] = *(const bf16x8*)((const char*)lP + ((trow * 256 + kbyte) ^ ((trow & 7) << 4)));
      }
#pragma unroll
      for (int n = 0; n < 2; ++n) {
        int drow = w * 32 + n * 16 + lrow;
        bv[n] = *(const bf16x8*)((const char*)lKV + ((drow * 256 + kbyte) ^ ((drow & 7) << 4)));
      }
#pragma unroll
      for (int m = 0; m < 2; ++m)
#pragma unroll
        for (int n = 0; n < 2; ++n)
          acc_o[m][n] = __builtin_amdgcn_mfma_f32_16x16x32_bf16(ap[m], bv[n], acc_o[m][n], 0, 0, 0);
    }
    __syncthreads();   // B5: P/V reads done before next K stage
  }

  if (lk == 0 && sh == 0) lFin[tcol] = l_run;
  __syncthreads();
#pragma unroll
  for (int m = 0; m < 2; ++m) {
    fvec4 s4 = *(const fvec4*)&lFin[m * 16 + lk * 4];
#pragma unroll
    for (int r = 0; r < 4; ++r) {
      float inv = 1.f / s4[r];
      int trow = t_lo + m * 16 + lk * 4 + r;
      u16* crow = ctx + (size_t)trow * (H_ * DH_) + h * DH_;
#pragma unroll
      for (int n = 0; n < 2; ++n) {
        int d = w * 32 + n * 16 + lrow;
        crow[d] = f2bf(acc_o[m][n][r] * inv);
      }
    }
  }
}

// ---------------- final RMS (last token) + 4-partial combine -----------------
__global__ void frms_k(const float* __restrict__ x, const float* __restrict__ p,
                       const float* __restrict__ w, float* __restrict__ out)
{
  __shared__ float sm[4];
  float s = 0.f;
  for (int d = threadIdx.x; d < D_; d += 256) {
    float v = x[d] + p[d] + p[ZSE + d] + p[2 * ZSE + d] + p[3 * ZSE + d];
    s += v * v;
  }
  s = blk_sum(s, sm);
  float inv = rsqrtf(s * (1.f / D_) + EPS_);
  for (int d = threadIdx.x; d < D_; d += 256)
    out[d] = w[d] * (x[d] + p[d] + p[ZSE + d] + p[2 * ZSE + d] + p[3 * ZSE + d]) * inv;
}

// ---------------- LM head partial GEMV (f32) ---------------------------------
__global__ void lmgemv_k(const float* __restrict__ last, const float* __restrict__ Wlm,
                         float* __restrict__ part)
{
  __shared__ float ls[256];
  int v = blockIdx.x * 256 + threadIdx.x;
  int c = blockIdx.y;
  ls[threadIdx.x] = last[c * 256 + threadIdx.x];
  __syncthreads();
  const float* Wp = Wlm + (size_t)c * 256 * V_ + v;
  float acc = 0.f;
#pragma unroll 8
  for (int d = 0; d < 256; d++) acc += ls[d] * Wp[(size_t)d * V_];
  part[(size_t)c * V_ + v] = acc;
}

__global__ void amax_part_k(const float* __restrict__ part, float2* __restrict__ out)
{
  __shared__ float sv[4];
  __shared__ int si[4];
  int v = blockIdx.x * 256 + threadIdx.x;
  float val = 0.f;
#pragma unroll
  for (int c = 0; c < 8; c++) val += part[(size_t)c * V_ + v];
  float bv = val; int bi = v;
#pragma unroll
  for (int m = 32; m; m >>= 1) {
    float ov = __shfl_xor(bv, m);
    int oi = __shfl_xor(bi, m);
    if (ov > bv || (ov == bv && oi < bi)) { bv = ov; bi = oi; }
  }
  if ((threadIdx.x & 63) == 0) { sv[threadIdx.x >> 6] = bv; si[threadIdx.x >> 6] = bi; }
  __syncthreads();
  if (threadIdx.x == 0) {
    for (int w = 1; w < 4; w++)
      if (sv[w] > bv || (sv[w] == bv && si[w] < bi)) { bv = sv[w]; bi = si[w]; }
    out[blockIdx.x] = make_float2(bv, (float)bi);
  }
}

__global__ void finalize_k(const float2* __restrict__ part, int np,
                           const int* __restrict__ plp, float* __restrict__ dout,
                           unsigned long long lastoff)
{
  if (threadIdx.x == 0) {
    float bv = part[0].x; int bi = (int)part[0].y;
    for (int b = 1; b < np; b++) {
      float v = part[b].x; int i = (int)part[b].y;
      if (v > bv || (v == bv && i < bi)) { bv = v; bi = i; }
    }
    dout[0] = (float)bi;
    dout[lastoff] = (float)(plp[0] + T_);
  }
}

// =============================================================================
extern "C" void kernel_launch(void* const* d_in, const int* in_sizes, int n_in,
                              void* d_out, int out_size, void* d_ws, size_t ws_size,
                              hipStream_t stream)
{
  (void)in_sizes; (void)n_in; (void)out_size; (void)ws_size;

  const float* key_in  = (const float*)d_in[0];
  const float* val_in  = (const float*)d_in[1];
  const int*   ids     = (const int*)d_in[2];
  const float* am      = (const float*)d_in[3];
  const int*   plp     = (const int*)d_in[4];
  const void*  edata   = d_in[5];
  const float* esc     = (const float*)d_in[6];
  const float* ez      = (const float*)d_in[7];
  const float* cosT    = (const float*)d_in[8];
  const float* sinT    = (const float*)d_in[9];
  const float* w_in_ln = (const float*)d_in[10];
  const float* Wq      = (const float*)d_in[11];
  const float* Wk      = (const float*)d_in[12];
  const float* Wv      = (const float*)d_in[13];
  const float* wqn     = (const float*)d_in[14];
  const float* wkn     = (const float*)d_in[15];
  const float* Wo      = (const float*)d_in[16];
  const float* wpost   = (const float*)d_in[17];
  const float* Wg      = (const float*)d_in[18];
  const float* Wu      = (const float*)d_in[19];
  const float* Wd      = (const float*)d_in[20];
  const float* wfin    = (const float*)d_in[21];
  const float* Wlm     = (const float*)d_in[22];

  float* out = (float*)d_out;
  const size_t KVN = (size_t)L_ * KVH_ * DH_ * SMAX_; // 8388608
  float* key_out = out + 1;
  float* val_out = out + 1 + KVN;
  unsigned long long lastoff = 1 + 2 * KVN;

  char* ws = (char*)d_ws;
  u16*   wT     = (u16*)  (ws + 0);            // 50,331,648
  u16*   hn     = (u16*)  (ws + 50331648);     //  4,194,304
  float* P      = (float*)(ws + 54525952);     // 67,108,864 (4 split-K planes)
  u16*   qr     = (u16*)  (ws + 121634816);    //  4,194,304
  u16*   kr     = (u16*)  (ws + 125829120);    //  2,097,152
  u16*   vT     = (u16*)  (ws + 127926272);    //  2,097,152
  u16*   ctx    = (u16*)  (ws + 130023424);    //  4,194,304
  float* hidden = (float*)(ws + 134217728);    //  8,388,608
  u16*   mlp    = (u16*)  (ws + 142606336);    // 12,582,912
  float* last   = (float*)(ws + 155189248);    //      8,192
  float* lpart  = (float*)(ws + 155197440);    //  1,024,000
  float2* amaxp = (float2*)(ws + 156221440);   //      4,096

  hipMemcpyAsync(key_out, key_in, KVN * sizeof(float), hipMemcpyDeviceToDevice, stream);
  hipMemcpyAsync(val_out, val_in, KVN * sizeof(float), hipMemcpyDeviceToDevice, stream);
  embed_k<<<T_, 256, 0, stream>>>(ids, edata, esc, ez, hidden);

  for (int i = 0; i < L_; i++) {
    // --- attention ---
    if (i == 0)
      rms_k<0><<<T_, 256, 0, stream>>>(hidden, nullptr, w_in_ln, hn);
    else
      rms_k<4><<<T_, 256, 0, stream>>>(hidden, P, w_in_ln + (size_t)i * D_, hn);

    convT2_k<<<dim3(64, 32), 256, 0, stream>>>(
        Wq + (size_t)i * 4194304, Wk + (size_t)i * 2097152, Wv + (size_t)i * 2097152,
        32, 48, 2048, 1024, 1024, 0, 2048, 3072, 2048, wT, 0);
    gemm_bt<0><<<dim3(32, 8, 2), 256, 0, stream>>>(hn, wT, P, nullptr, 2048, 1024, 4096, ZSE);

    qkvpost_k<<<dim3(T_ / 64, 32), 256, 0, stream>>>(P, P + ZSE,
        wqn + (size_t)i * DH_, wkn + (size_t)i * DH_, cosT, sinT, plp,
        qr, kr, vT,
        key_out + (size_t)i * KVH_ * DH_ * SMAX_,
        val_out + (size_t)i * KVH_ * SMAX_ * DH_);

    flash_k<<<dim3(T_ / QB, H_), 256, 0, stream>>>(qr, kr, vT, am, plp, ctx);

    convT2_k<<<dim3(32, 32), 256, 0, stream>>>(
        Wo + (size_t)i * 4194304, nullptr, nullptr,
        32, 64, 2048, 2048, 2048, 0, 0, 0, 2048, wT, 0);
    gemm_bt<0><<<dim3(16, 8, 4), 256, 0, stream>>>(ctx, wT, P, nullptr, 2048, 512, 2048, ZSE);

    // --- MLP ---
    rms_k<4><<<T_, 256, 0, stream>>>(hidden, P, wpost + (size_t)i * D_, hn);

    convT2_k<<<dim3(192, 32), 256, 0, stream>>>(
        Wg + (size_t)i * 12582912, Wu + (size_t)i * 12582912, Wu + (size_t)i * 12582912,
        96, 192, 6144, 6144, 6144, 0, 16, 16, 2048, wT, 1);
    gemm_bt<3><<<dim3(96, 8, 1), 256, 0, stream>>>(hn, wT, nullptr, mlp, 2048, 2048, 6144, 0);

    convT2_k<<<dim3(32, 96), 256, 0, stream>>>(
        Wd + (size_t)i * 12582912, nullptr, nullptr,
        32, 64, 2048, 2048, 2048, 0, 0, 0, 6144, wT, 0);
    gemm_bt<0><<<dim3(16, 8, 4), 256, 0, stream>>>(mlp, wT, P, nullptr, 6144, 1536, 2048, ZSE);
  }

  frms_k<<<1, 256, 0, stream>>>(hidden + (size_t)(T_ - 1) * D_,
                                P + (size_t)(T_ - 1) * D_, wfin, last);
  lmgemv_k<<<dim3(V_ / 256, 8), 256, 0, stream>>>(last, Wlm, lpart);
  amax_part_k<<<V_ / 256, 256, 0, stream>>>(lpart, amaxp);
  finalize_k<<<1, 64, 0, stream>>>(amaxp, V_ / 256, plp, out, lastoff);
}